// Round 6
// baseline (1399.137 us; speedup 1.0000x reference)
//
#include <hip/hip_runtime.h>
#include <hip/hip_bf16.h>
#include <math.h>

#define IC 512
#define OC 512
#define STYLE 512
#define BB 8
#define H_ 64
#define W_ 64
#define HW 4096
#define HP 66          // padded rows (zero row above and below)
#define KC 32          // channel chunk per MFMA K-step
#define NCHUNK 16
#define USTRIDE 1056   // bytes per u-granule plane in conv LDS: 66 cols * 16B
#define ROWSTRIDE 4224 // 4 * USTRIDE
#define BUFSZ (6 * ROWSTRIDE)   // 25344 B per x buffer

typedef __attribute__((ext_vector_type(8))) __bf16 bf16x8;
typedef __attribute__((ext_vector_type(4))) float floatx4;

static __device__ __forceinline__ unsigned short f2bf(float f) {
    unsigned u = __builtin_bit_cast(unsigned, f);
    unsigned r = u + 0x7FFFu + ((u >> 16) & 1u);   // RNE
    return (unsigned short)(r >> 16);
}

// async global->LDS DMA, 16B per lane. dst is wave-uniform base; HW writes lane i at dst + i*16.
static __device__ __forceinline__ void gload_lds16(const unsigned short* g, unsigned char* l) {
    __builtin_amdgcn_global_load_lds((const __attribute__((address_space(1))) unsigned int*)g,
                                     (__attribute__((address_space(3))) unsigned int*)l,
                                     16, 0, 0);
}

// ---------------- K1: s[b,i] = MOD_SCALE * style[b,:]·(mod_weight + fcB@fcA^T)[i,:] + biases
__global__ void k_style(const float* __restrict__ style, const float* __restrict__ mod_weight,
                        const float* __restrict__ mod_bias, const float* __restrict__ fc_lora_A,
                        const float* __restrict__ fc_lora_B, const float* __restrict__ fc_lora_bias,
                        float* __restrict__ s_out) {
    int b = blockIdx.y;
    int i = blockIdx.x * 16 + (threadIdx.x >> 4);
    int jg = threadIdx.x & 15;
    float4 fb = *(const float4*)&fc_lora_B[i * 4];
    const float* st = style + b * STYLE;
    const float* mw = mod_weight + (size_t)i * STYLE;
    float acc = 0.f;
    for (int j = jg * 32; j < jg * 32 + 32; ++j) {
        float4 fa = *(const float4*)&fc_lora_A[j * 4];
        float w = mw[j] + fb.x * fa.x + fb.y * fa.y + fb.z * fa.z + fb.w * fa.w;
        acc += st[j] * w;
    }
    #pragma unroll
    for (int off = 8; off; off >>= 1) acc += __shfl_down(acc, off, 16);
    if (jg == 0) {
        float mod_scale = 1.0f / sqrtf((float)STYLE);
        s_out[b * IC + i] = mod_scale * acc + mod_bias[i] + fc_lora_bias[i];
    }
}

// ---------------- K2: w5 = weight + relu(A·relu(B·inst)); wb swizzled for MFMA A-frags; W2[o][i]
// wb layout: [t(9)][ot(8)][mt(4)][ci(16)][lane(64)][8]
__global__ void k_weight(const float* __restrict__ weight, const float* __restrict__ llB,
                         const float* __restrict__ llBinst, const float* __restrict__ llA,
                         unsigned short* __restrict__ wb, float* __restrict__ W2) {
    int gid = blockIdx.x * 256 + threadIdx.x;      // 262144
    int o = gid >> 9, i = gid & 511;
    float4 vB = *(const float4*)&llB[o * 4];
    float4 vA = *(const float4*)&llA[i * 4];
    const float* wrow = weight + (size_t)(o * IC + i) * 9;
    int lane = ((i >> 3) & 3) * 16 + (o & 15);
    size_t wbase = (((size_t)((o >> 6) * 4 + ((o >> 4) & 3)) * 16 + (i >> 5)) * 64 + lane) * 8 + (i & 7);
    float w2 = 0.f;
    #pragma unroll
    for (int k = 0; k < 9; ++k) {
        float wadd = 0.f;
        #pragma unroll
        for (int bb = 0; bb < 4; ++bb) {
            float bm = vB.x * llBinst[(bb * 4 + 0) * 9 + k] + vB.y * llBinst[(bb * 4 + 1) * 9 + k]
                     + vB.z * llBinst[(bb * 4 + 2) * 9 + k] + vB.w * llBinst[(bb * 4 + 3) * 9 + k];
            bm = fmaxf(bm, 0.f);
            float a = (bb == 0) ? vA.x : (bb == 1) ? vA.y : (bb == 2) ? vA.z : vA.w;
            wadd += a * bm;
        }
        wadd = fmaxf(wadd, 0.f);
        float w5 = wrow[k] + wadd;                 // LORA_ALPHA_CONV = 1
        wb[(size_t)k * 262144 + wbase] = f2bf(w5);
        w2 += w5 * w5;
    }
    W2[gid] = w2;
}

// ---------------- K3: scale[b][o] = CONV_SCALE * rsqrt(CONV_SCALE^2 * sum_i W2[o,i]*s[b,i]^2 + eps)
__global__ void k_scale(const float* __restrict__ W2, const float* __restrict__ s,
                        float* __restrict__ scale) {
    int b = blockIdx.y;
    int o = blockIdx.x * 16 + (threadIdx.x >> 4);
    int jg = threadIdx.x & 15;
    const float* w2r = W2 + (size_t)o * IC;
    const float* sr = s + b * IC;
    float acc = 0.f;
    for (int i = jg * 32; i < jg * 32 + 32; ++i) { float sv = sr[i]; acc += w2r[i] * sv * sv; }
    #pragma unroll
    for (int off = 8; off; off >>= 1) acc += __shfl_down(acc, off, 16);
    if (jg == 0) {
        float cs = 1.0f / sqrtf((float)(IC * 9));
        scale[b * OC + o] = cs * rsqrtf(cs * cs * acc + 1e-8f);
    }
}

// ---------------- K4: NCHW fp32 -> xm[b][hp][ci(16)][u(4)][w(64)][8ch] bf16, modulated by s
__global__ void k_stage_x(const float* __restrict__ x, const float* __restrict__ s,
                          unsigned short* __restrict__ xm) {
    __shared__ float tile[128 * 65];
    int cc = blockIdx.x;   // 0..3 (128-channel chunk)
    int hp = blockIdx.y;   // 0..65
    int b  = blockIdx.z;
    int c0 = cc * 128;
    int tid = threadIdx.x;
    if (hp == 0 || hp == HP - 1) {
        unsigned short* dst = xm + (size_t)(b * HP + hp) * 32768 + cc * 8192;
        uint4 z = make_uint4(0, 0, 0, 0);
        #pragma unroll
        for (int p = 0; p < 4; ++p)
            *(uint4*)(dst + (size_t)(p * 256 + tid) * 8) = z;
        return;
    }
    int h = hp - 1;
    const float* xin = x + (((size_t)b * IC + c0) * H_ + h) * W_;
    #pragma unroll
    for (int p = 0; p < 32; ++p) {
        int idx = p * 256 + tid;
        int c = idx >> 6, w = idx & 63;
        tile[c * 65 + w] = xin[(size_t)c * HW + w];
    }
    __syncthreads();
    const float* sb = s + b * IC + c0;
    #pragma unroll
    for (int p = 0; p < 4; ++p) {
        int idx = p * 256 + tid;               // 0..1023
        int cil = idx >> 8;                    // local ci 0..3
        int u   = (idx >> 6) & 3;
        int w   = idx & 63;
        int cb  = cil * 32 + u * 8;
        unsigned int packed[4];
        #pragma unroll
        for (int k = 0; k < 4; ++k) {
            unsigned lo = f2bf(tile[(cb + 2 * k) * 65 + w] * sb[cb + 2 * k]);
            unsigned hi = f2bf(tile[(cb + 2 * k + 1) * 65 + w] * sb[cb + 2 * k + 1]);
            packed[k] = lo | (hi << 16);
        }
        size_t g = (((size_t)(b * HP + hp) * 16 + (cc * 4 + cil)) * 4 + u) * 64 + w;
        *(uint4*)(xm + g * 8) = make_uint4(packed[0], packed[1], packed[2], packed[3]);
    }
}

// ---------------- K5: conv. R3 structure (256 thr, 4 waves, 3 blocks/CU, 1024 blocks,
// ot = wgid%8 XCD-pinned) + register-double-buffered weights: afA/afB hold the full
// 36-fragment weight set for the current/next chunk, loaded one full chunk ahead so
// the af L2 latency+BW bursts leave the critical path entirely.
#define STAGE(CN, BSEL)                                                                          \
    _Pragma("unroll")                                                                            \
    for (int j = 0; j < 6; ++j)                                                                  \
        gload_lds16(xmb + ((((size_t)(h0 + j) * 16 + (CN)) * 4 + wave) * 64 + lane) * 8,         \
                    xs + (size_t)(BSEL) * BUFSZ + (size_t)j * ROWSTRIDE + wave * USTRIDE + 16);

#define LOADAF(AF, CN)                                                                           \
    {   const unsigned short* wlc_ = wlb + (size_t)(CN) * 512;                                   \
        _Pragma("unroll")                                                                        \
        for (int t = 0; t < 9; ++t)                                                              \
            _Pragma("unroll")                                                                    \
            for (int mt = 0; mt < 4; ++mt)                                                       \
                (AF)[t][mt] = *(const bf16x8*)(wlc_ + (size_t)t * 262144 + mt * 8192);           \
    }

#define COMPUTE(AF, BSEL)                                                                        \
    {   const unsigned char* buf_ = xs + (size_t)(BSEL) * BUFSZ;                                 \
        _Pragma("unroll")                                                                        \
        for (int kh = 0; kh < 3; ++kh)                                                           \
            _Pragma("unroll")                                                                    \
            for (int dw = 0; dw < 3; ++dw) {                                                     \
                const int t = kh * 3 + dw;                                                       \
                bf16x8 bv[4];                                                                    \
                _Pragma("unroll")                                                                \
                for (int nt = 0; nt < 4; ++nt)                                                   \
                    bv[nt] = *(const bf16x8*)(buf_ + (size_t)(wave + kh) * ROWSTRIDE             \
                                              + lq * USTRIDE + (nt * 16 + l16 + dw) * 16);       \
                _Pragma("unroll")                                                                \
                for (int mt = 0; mt < 4; ++mt)                                                   \
                    _Pragma("unroll")                                                            \
                    for (int nt = 0; nt < 4; ++nt)                                               \
                        acc[mt][nt] = __builtin_amdgcn_mfma_f32_16x16x32_bf16((AF)[t][mt],       \
                                          bv[nt], acc[mt][nt], 0, 0, 0);                         \
            }                                                                                    \
    }

__global__ __launch_bounds__(256, 3) void k_conv(const unsigned short* __restrict__ wb,
                                                 const unsigned short* __restrict__ xm,
                                                 const float* __restrict__ scale,
                                                 float* __restrict__ out) {
    __shared__ unsigned char xs[2 * BUFSZ];        // 50688 B; epilogue reuses (17408 B)
    const int tid = threadIdx.x;
    const int wave = tid >> 6, lane = tid & 63;
    const int l16 = lane & 15, lq = lane >> 4;
    const int wgid = blockIdx.x;        // 0..1023
    const int ot = wgid & 7;            // 0..7  -> pinned to XCD (wgid % 8)
    const int r  = wgid >> 3;           // 0..127
    const int ht = r & 15;              // 0..15 (fastest within XCD)
    const int b  = r >> 4;              // 0..7
    const int om = ot * 64;
    const int h0 = ht * 4;

    // zero border col-granules (cols 0 and 65, all 6 rows, all u, BOTH buffers): 96 x 16B
    if (tid < 96) {
        int bsel = tid >= 48;
        int t48 = tid - bsel * 48;
        int row = t48 >> 3;
        int rem = t48 & 7;
        int u = rem >> 1;
        int side = rem & 1;
        uint4 z = make_uint4(0, 0, 0, 0);
        *(uint4*)(xs + bsel * BUFSZ + row * ROWSTRIDE + u * USTRIDE + side * 65 * 16) = z;
    }

    floatx4 acc[4][4];
    #pragma unroll
    for (int mt = 0; mt < 4; ++mt)
        #pragma unroll
        for (int nt = 0; nt < 4; ++nt)
            acc[mt][nt] = (floatx4){0.f, 0.f, 0.f, 0.f};

    // x staging: wave `wave` handles channel-granule u=wave; DMA writes lanes at dst+lane*16
    // (cols 1..64; border cols 0/65 hold the pre-written zeros).
    const unsigned short* xmb = xm + (size_t)b * HP * 32768;
    // weights: swizzled so per-wave load is base + lane*16B (coalesced)
    const unsigned short* wlb = wb + (size_t)ot * 32768 + (size_t)lane * 8;

    // prologue: DMA chunk 0 into buffer 0; preload chunk 0's weights into afA
    STAGE(0, 0)
    bf16x8 afA[9][4], afB[9][4];
    LOADAF(afA, 0)

    for (int ci = 0; ci < NCHUNK; ci += 2) {
        __syncthreads();                // buf0 (chunk ci) staged; afA (chunk ci) loaded
        STAGE(ci + 1, 1)                // in flight across compute(ci)
        LOADAF(afB, ci + 1)             // in flight across compute(ci)
        COMPUTE(afA, 0)
        __syncthreads();                // buf1 (chunk ci+1) staged
        if (ci + 2 < NCHUNK) {
            STAGE(ci + 2, 0)
            LOADAF(afA, ci + 2)
        }
        COMPUTE(afB, 1)
    }

    // ---- epilogue: scale, then stage through LDS for fully-coalesced float4 stores
    __syncthreads();                    // all waves done with both x buffers
    float* ebuf = (float*)xs + wave * 1088;        // 16 rows x 68 floats per wave
    const int h = h0 + wave;
    const float* scb = scale + b * OC + om;
    #pragma unroll
    for (int mt = 0; mt < 4; ++mt) {
        float4 sc = *(const float4*)&scb[mt * 16 + lq * 4];
        const float* scp = (const float*)&sc;
        #pragma unroll
        for (int nt = 0; nt < 4; ++nt)
            #pragma unroll
            for (int r2 = 0; r2 < 4; ++r2)
                ebuf[(lq * 4 + r2) * 68 + nt * 16 + l16] = acc[mt][nt][r2] * scp[r2];
        __syncthreads();                // uniform; guarantees write->read ordering
        #pragma unroll
        for (int q = 0; q < 4; ++q) {
            int r0 = q * 4 + (lane >> 4);
            int c0 = (lane & 15) * 4;
            float4 v = *(float4*)&ebuf[r0 * 68 + c0];
            *(float4*)&out[((size_t)(b * OC + om + mt * 16 + r0)) * HW + h * W_ + c0] = v;
        }
        __syncthreads();                // reads done before next mt's writes
    }
}

extern "C" void kernel_launch(void* const* d_in, const int* in_sizes, int n_in,
                              void* d_out, int out_size, void* d_ws, size_t ws_size,
                              hipStream_t stream) {
    const float* input   = (const float*)d_in[0];
    const float* style   = (const float*)d_in[1];
    const float* weight  = (const float*)d_in[2];
    const float* llB     = (const float*)d_in[3];
    const float* llBinst = (const float*)d_in[4];
    const float* llA     = (const float*)d_in[5];
    const float* mod_w   = (const float*)d_in[6];
    const float* mod_b   = (const float*)d_in[7];
    const float* fcA     = (const float*)d_in[8];
    const float* fcB     = (const float*)d_in[9];
    const float* fcBias  = (const float*)d_in[10];
    float* out = (float*)d_out;

    char* ws = (char*)d_ws;
    float* s_ws            = (float*)(ws + 0);                  // 16 KB
    float* scale_ws        = (float*)(ws + 16384);              // 16 KB
    float* W2_ws           = (float*)(ws + 32768);              // 1 MB
    unsigned short* wb_ws  = (unsigned short*)(ws + 32768 + 1048576);          // 4.72 MB
    unsigned short* xm_ws  = (unsigned short*)(ws + 32768 + 1048576 + 4718592); // 34.6 MB

    k_style<<<dim3(32, 8), 256, 0, stream>>>(style, mod_w, mod_b, fcA, fcB, fcBias, s_ws);
    k_weight<<<1024, 256, 0, stream>>>(weight, llB, llBinst, llA, wb_ws, W2_ws);
    k_scale<<<dim3(32, 8), 256, 0, stream>>>(W2_ws, s_ws, scale_ws);
    k_stage_x<<<dim3(4, 66, 8), 256, 0, stream>>>(input, s_ws, xm_ws);
    k_conv<<<1024, 256, 0, stream>>>(wb_ws, xm_ws, scale_ws, out);
}

// Round 7
// 331.249 us; speedup vs baseline: 4.2238x; 4.2238x over previous
//
#include <hip/hip_runtime.h>
#include <hip/hip_bf16.h>
#include <math.h>

#define IC 512
#define OC 512
#define STYLE 512
#define BB 8
#define H_ 64
#define W_ 64
#define HW 4096
#define HP 66          // padded rows (zero row above and below)
#define KC 32          // channel chunk per MFMA K-step
#define NCHUNK 16
#define USTRIDE 1056   // bytes per u-granule plane in conv LDS: 66 cols * 16B
#define ROWSTRIDE 4224 // 4 * USTRIDE
#define BUFSZ (6 * ROWSTRIDE)   // 25344 B per x buffer

typedef __attribute__((ext_vector_type(8))) __bf16 bf16x8;
typedef __attribute__((ext_vector_type(4))) float floatx4;

static __device__ __forceinline__ unsigned short f2bf(float f) {
    unsigned u = __builtin_bit_cast(unsigned, f);
    unsigned r = u + 0x7FFFu + ((u >> 16) & 1u);   // RNE
    return (unsigned short)(r >> 16);
}

// async global->LDS DMA, 16B per lane. dst is wave-uniform base; HW writes lane i at dst + i*16.
static __device__ __forceinline__ void gload_lds16(const unsigned short* g, unsigned char* l) {
    __builtin_amdgcn_global_load_lds((const __attribute__((address_space(1))) unsigned int*)g,
                                     (__attribute__((address_space(3))) unsigned int*)l,
                                     16, 0, 0);
}

// ---------------- K1: s[b,i] = MOD_SCALE * style[b,:]·(mod_weight + fcB@fcA^T)[i,:] + biases
__global__ void k_style(const float* __restrict__ style, const float* __restrict__ mod_weight,
                        const float* __restrict__ mod_bias, const float* __restrict__ fc_lora_A,
                        const float* __restrict__ fc_lora_B, const float* __restrict__ fc_lora_bias,
                        float* __restrict__ s_out) {
    int b = blockIdx.y;
    int i = blockIdx.x * 16 + (threadIdx.x >> 4);
    int jg = threadIdx.x & 15;
    float4 fb = *(const float4*)&fc_lora_B[i * 4];
    const float* st = style + b * STYLE;
    const float* mw = mod_weight + (size_t)i * STYLE;
    float acc = 0.f;
    for (int j = jg * 32; j < jg * 32 + 32; ++j) {
        float4 fa = *(const float4*)&fc_lora_A[j * 4];
        float w = mw[j] + fb.x * fa.x + fb.y * fa.y + fb.z * fa.z + fb.w * fa.w;
        acc += st[j] * w;
    }
    #pragma unroll
    for (int off = 8; off; off >>= 1) acc += __shfl_down(acc, off, 16);
    if (jg == 0) {
        float mod_scale = 1.0f / sqrtf((float)STYLE);
        s_out[b * IC + i] = mod_scale * acc + mod_bias[i] + fc_lora_bias[i];
    }
}

// ---------------- K2: w5 = weight + relu(A·relu(B·inst)); wb swizzled for MFMA A-frags; W2[o][i]
// wb layout: [t(9)][ot(8)][mt(4)][ci(16)][lane(64)][8]
__global__ void k_weight(const float* __restrict__ weight, const float* __restrict__ llB,
                         const float* __restrict__ llBinst, const float* __restrict__ llA,
                         unsigned short* __restrict__ wb, float* __restrict__ W2) {
    int gid = blockIdx.x * 256 + threadIdx.x;      // 262144
    int o = gid >> 9, i = gid & 511;
    float4 vB = *(const float4*)&llB[o * 4];
    float4 vA = *(const float4*)&llA[i * 4];
    const float* wrow = weight + (size_t)(o * IC + i) * 9;
    int lane = ((i >> 3) & 3) * 16 + (o & 15);
    size_t wbase = (((size_t)((o >> 6) * 4 + ((o >> 4) & 3)) * 16 + (i >> 5)) * 64 + lane) * 8 + (i & 7);
    float w2 = 0.f;
    #pragma unroll
    for (int k = 0; k < 9; ++k) {
        float wadd = 0.f;
        #pragma unroll
        for (int bb = 0; bb < 4; ++bb) {
            float bm = vB.x * llBinst[(bb * 4 + 0) * 9 + k] + vB.y * llBinst[(bb * 4 + 1) * 9 + k]
                     + vB.z * llBinst[(bb * 4 + 2) * 9 + k] + vB.w * llBinst[(bb * 4 + 3) * 9 + k];
            bm = fmaxf(bm, 0.f);
            float a = (bb == 0) ? vA.x : (bb == 1) ? vA.y : (bb == 2) ? vA.z : vA.w;
            wadd += a * bm;
        }
        wadd = fmaxf(wadd, 0.f);
        float w5 = wrow[k] + wadd;                 // LORA_ALPHA_CONV = 1
        wb[(size_t)k * 262144 + wbase] = f2bf(w5);
        w2 += w5 * w5;
    }
    W2[gid] = w2;
}

// ---------------- K3: scale[b][o] = CONV_SCALE * rsqrt(CONV_SCALE^2 * sum_i W2[o,i]*s[b,i]^2 + eps)
__global__ void k_scale(const float* __restrict__ W2, const float* __restrict__ s,
                        float* __restrict__ scale) {
    int b = blockIdx.y;
    int o = blockIdx.x * 16 + (threadIdx.x >> 4);
    int jg = threadIdx.x & 15;
    const float* w2r = W2 + (size_t)o * IC;
    const float* sr = s + b * IC;
    float acc = 0.f;
    for (int i = jg * 32; i < jg * 32 + 32; ++i) { float sv = sr[i]; acc += w2r[i] * sv * sv; }
    #pragma unroll
    for (int off = 8; off; off >>= 1) acc += __shfl_down(acc, off, 16);
    if (jg == 0) {
        float cs = 1.0f / sqrtf((float)(IC * 9));
        scale[b * OC + o] = cs * rsqrtf(cs * cs * acc + 1e-8f);
    }
}

// ---------------- K4: NCHW fp32 -> xm[b][hp][ci(16)][u(4)][w(64)][8ch] bf16, modulated by s
__global__ void k_stage_x(const float* __restrict__ x, const float* __restrict__ s,
                          unsigned short* __restrict__ xm) {
    __shared__ float tile[128 * 65];
    int cc = blockIdx.x;   // 0..3 (128-channel chunk)
    int hp = blockIdx.y;   // 0..65
    int b  = blockIdx.z;
    int c0 = cc * 128;
    int tid = threadIdx.x;
    if (hp == 0 || hp == HP - 1) {
        unsigned short* dst = xm + (size_t)(b * HP + hp) * 32768 + cc * 8192;
        uint4 z = make_uint4(0, 0, 0, 0);
        #pragma unroll
        for (int p = 0; p < 4; ++p)
            *(uint4*)(dst + (size_t)(p * 256 + tid) * 8) = z;
        return;
    }
    int h = hp - 1;
    const float* xin = x + (((size_t)b * IC + c0) * H_ + h) * W_;
    #pragma unroll
    for (int p = 0; p < 32; ++p) {
        int idx = p * 256 + tid;
        int c = idx >> 6, w = idx & 63;
        tile[c * 65 + w] = xin[(size_t)c * HW + w];
    }
    __syncthreads();
    const float* sb = s + b * IC + c0;
    #pragma unroll
    for (int p = 0; p < 4; ++p) {
        int idx = p * 256 + tid;               // 0..1023
        int cil = idx >> 8;                    // local ci 0..3
        int u   = (idx >> 6) & 3;
        int w   = idx & 63;
        int cb  = cil * 32 + u * 8;
        unsigned int packed[4];
        #pragma unroll
        for (int k = 0; k < 4; ++k) {
            unsigned lo = f2bf(tile[(cb + 2 * k) * 65 + w] * sb[cb + 2 * k]);
            unsigned hi = f2bf(tile[(cb + 2 * k + 1) * 65 + w] * sb[cb + 2 * k + 1]);
            packed[k] = lo | (hi << 16);
        }
        size_t g = (((size_t)(b * HP + hp) * 16 + (cc * 4 + cil)) * 4 + u) * 64 + w;
        *(uint4*)(xm + g * 8) = make_uint4(packed[0], packed[1], packed[2], packed[3]);
    }
}

// ---------------- K5: conv. R3 structure (256 thr, 4 waves, 3 blocks/CU, 1024 blocks,
// ot = wgid%8 XCD-pinned, 2-phase x DMA pipeline) + 3-deep rotating af prefetch:
// at t-step t, the load for t+2 is issued while MFMAs of t run on the set loaded 2 steps
// ago. 9 steps % 3 == 0 -> rotation closes with no copies; the last 2 loads prefetch the
// NEXT chunk's t0/t1, so no af stall at chunk start. Only 48 af VGPRs (fits 168-reg cap;
// the R6 full-chunk double-buffer needed 288 and spilled to scratch -> 1300 us).
#define STAGE(CN, BSEL)                                                                          \
    _Pragma("unroll")                                                                            \
    for (int j = 0; j < 6; ++j)                                                                  \
        gload_lds16(xmb + ((((size_t)(h0 + j) * 16 + (CN)) * 4 + wave) * 64 + lane) * 8,         \
                    xs + (size_t)(BSEL) * BUFSZ + (size_t)j * ROWSTRIDE + wave * USTRIDE + 16);

// load af fragment set for (chunk CN, tap T) — T is a literal at every expansion site
#define LOADT(AF, CN, T)                                                                         \
    _Pragma("unroll")                                                                            \
    for (int mt = 0; mt < 4; ++mt)                                                               \
        (AF)[mt] = *(const bf16x8*)(wlb + (size_t)(T) * 262144 + (size_t)(CN) * 512 + mt * 8192);

// one tap: 4 bv ds_reads + 16 MFMAs using fragment set AF (loaded 2 taps earlier)
#define BODY(AF, T)                                                                              \
    {   const int kh_ = (T) / 3, dw_ = (T) % 3;                                                  \
        bf16x8 bv[4];                                                                            \
        _Pragma("unroll")                                                                        \
        for (int nt = 0; nt < 4; ++nt)                                                           \
            bv[nt] = *(const bf16x8*)(bufc + (size_t)(wave + kh_) * ROWSTRIDE                    \
                                      + lq * USTRIDE + (nt * 16 + l16 + dw_) * 16);              \
        _Pragma("unroll")                                                                        \
        for (int mt = 0; mt < 4; ++mt)                                                           \
            _Pragma("unroll")                                                                    \
            for (int nt = 0; nt < 4; ++nt)                                                       \
                acc[mt][nt] = __builtin_amdgcn_mfma_f32_16x16x32_bf16((AF)[mt], bv[nt],          \
                                                                      acc[mt][nt], 0, 0, 0);     \
    }

__global__ __launch_bounds__(256, 3) void k_conv(const unsigned short* __restrict__ wb,
                                                 const unsigned short* __restrict__ xm,
                                                 const float* __restrict__ scale,
                                                 float* __restrict__ out) {
    __shared__ unsigned char xs[2 * BUFSZ];        // 50688 B; epilogue reuses (17408 B)
    const int tid = threadIdx.x;
    const int wave = tid >> 6, lane = tid & 63;
    const int l16 = lane & 15, lq = lane >> 4;
    const int wgid = blockIdx.x;        // 0..1023
    const int ot = wgid & 7;            // 0..7  -> pinned to XCD (wgid % 8)
    const int r  = wgid >> 3;           // 0..127
    const int ht = r & 15;              // 0..15 (fastest within XCD)
    const int b  = r >> 4;              // 0..7
    const int om = ot * 64;
    const int h0 = ht * 4;

    // zero border col-granules (cols 0 and 65, all 6 rows, all u, BOTH buffers): 96 x 16B
    if (tid < 96) {
        int bsel = tid >= 48;
        int t48 = tid - bsel * 48;
        int row = t48 >> 3;
        int rem = t48 & 7;
        int u = rem >> 1;
        int side = rem & 1;
        uint4 z = make_uint4(0, 0, 0, 0);
        *(uint4*)(xs + bsel * BUFSZ + row * ROWSTRIDE + u * USTRIDE + side * 65 * 16) = z;
    }

    floatx4 acc[4][4];
    #pragma unroll
    for (int mt = 0; mt < 4; ++mt)
        #pragma unroll
        for (int nt = 0; nt < 4; ++nt)
            acc[mt][nt] = (floatx4){0.f, 0.f, 0.f, 0.f};

    // x staging: wave `wave` handles channel-granule u=wave; DMA writes lanes at dst+lane*16
    // (cols 1..64; border cols 0/65 hold the pre-written zeros).
    const unsigned short* xmb = xm + (size_t)b * HP * 32768;
    // weights: swizzled so per-wave load is base + lane*16B (coalesced)
    const unsigned short* wlb = wb + (size_t)ot * 32768 + (size_t)lane * 8;

    // prologue: DMA chunk 0 into buffer 0; preload chunk 0 taps 0,1 into A,B
    STAGE(0, 0)
    bf16x8 afA[4], afB[4], afC[4];
    LOADT(afA, 0, 0)
    LOADT(afB, 0, 1)

    int cur = 0;
    for (int ci = 0; ci < NCHUNK; ++ci) {
        __syncthreads();                // buf[cur] staged (implicit vmcnt(0) drains DMA)
        if (ci + 1 < NCHUNK) STAGE(ci + 1, cur ^ 1)   // in flight across compute(ci)
        const unsigned char* bufc = xs + (size_t)cur * BUFSZ;
        const int cn = (ci + 1) & 15;   // next chunk (wraps at 15; wrap values unused)
        // invariant at entry: A = (ci,t0), B = (ci,t1); loads issued >=2 taps earlier
        LOADT(afC, ci, 2)  BODY(afA, 0)
        LOADT(afA, ci, 3)  BODY(afB, 1)
        LOADT(afB, ci, 4)  BODY(afC, 2)
        LOADT(afC, ci, 5)  BODY(afA, 3)
        LOADT(afA, ci, 6)  BODY(afB, 4)
        LOADT(afB, ci, 7)  BODY(afC, 5)
        LOADT(afC, ci, 8)  BODY(afA, 6)
        LOADT(afA, cn, 0)  BODY(afB, 7)
        LOADT(afB, cn, 1)  BODY(afC, 8)
        // rotation closed: A = (cn,t0), B = (cn,t1) — invariant restored, no copies
        cur ^= 1;
    }

    // ---- epilogue: scale, then stage through LDS for fully-coalesced float4 stores
    __syncthreads();                    // all waves done with both x buffers
    float* ebuf = (float*)xs + wave * 1088;        // 16 rows x 68 floats per wave
    const int h = h0 + wave;
    const float* scb = scale + b * OC + om;
    #pragma unroll
    for (int mt = 0; mt < 4; ++mt) {
        float4 sc = *(const float4*)&scb[mt * 16 + lq * 4];
        const float* scp = (const float*)&sc;
        #pragma unroll
        for (int nt = 0; nt < 4; ++nt)
            #pragma unroll
            for (int r2 = 0; r2 < 4; ++r2)
                ebuf[(lq * 4 + r2) * 68 + nt * 16 + l16] = acc[mt][nt][r2] * scp[r2];
        __syncthreads();                // uniform; guarantees write->read ordering
        #pragma unroll
        for (int q = 0; q < 4; ++q) {
            int r0 = q * 4 + (lane >> 4);
            int c0 = (lane & 15) * 4;
            float4 v = *(float4*)&ebuf[r0 * 68 + c0];
            *(float4*)&out[((size_t)(b * OC + om + mt * 16 + r0)) * HW + h * W_ + c0] = v;
        }
        __syncthreads();                // reads done before next mt's writes
    }
}

extern "C" void kernel_launch(void* const* d_in, const int* in_sizes, int n_in,
                              void* d_out, int out_size, void* d_ws, size_t ws_size,
                              hipStream_t stream) {
    const float* input   = (const float*)d_in[0];
    const float* style   = (const float*)d_in[1];
    const float* weight  = (const float*)d_in[2];
    const float* llB     = (const float*)d_in[3];
    const float* llBinst = (const float*)d_in[4];
    const float* llA     = (const float*)d_in[5];
    const float* mod_w   = (const float*)d_in[6];
    const float* mod_b   = (const float*)d_in[7];
    const float* fcA     = (const float*)d_in[8];
    const float* fcB     = (const float*)d_in[9];
    const float* fcBias  = (const float*)d_in[10];
    float* out = (float*)d_out;

    char* ws = (char*)d_ws;
    float* s_ws            = (float*)(ws + 0);                  // 16 KB
    float* scale_ws        = (float*)(ws + 16384);              // 16 KB
    float* W2_ws           = (float*)(ws + 32768);              // 1 MB
    unsigned short* wb_ws  = (unsigned short*)(ws + 32768 + 1048576);          // 4.72 MB
    unsigned short* xm_ws  = (unsigned short*)(ws + 32768 + 1048576 + 4718592); // 34.6 MB

    k_style<<<dim3(32, 8), 256, 0, stream>>>(style, mod_w, mod_b, fcA, fcB, fcBias, s_ws);
    k_weight<<<1024, 256, 0, stream>>>(weight, llB, llBinst, llA, wb_ws, W2_ws);
    k_scale<<<dim3(32, 8), 256, 0, stream>>>(W2_ws, s_ws, scale_ws);
    k_stage_x<<<dim3(4, 66, 8), 256, 0, stream>>>(input, s_ws, xm_ws);
    k_conv<<<1024, 256, 0, stream>>>(wb_ws, xm_ws, scale_ws, out);
}

// Round 9
// 321.892 us; speedup vs baseline: 4.3466x; 1.0291x over previous
//
#include <hip/hip_runtime.h>
#include <hip/hip_bf16.h>
#include <math.h>

#define IC 512
#define OC 512
#define STYLE 512
#define BB 8
#define H_ 64
#define W_ 64
#define HW 4096
#define HP 66          // padded rows (zero row above and below)
#define KC 32          // channel chunk per MFMA K-step
#define NCHUNK 16
#define USTRIDE 1056   // bytes per u-granule plane in conv LDS: 66 cols * 16B
#define ROWSTRIDE 4224 // 4 * USTRIDE
#define BUFSZ (6 * ROWSTRIDE)   // 25344 B per x buffer

typedef __attribute__((ext_vector_type(8))) __bf16 bf16x8;
typedef __attribute__((ext_vector_type(4))) float floatx4;

static __device__ __forceinline__ unsigned short f2bf(float f) {
    unsigned u = __builtin_bit_cast(unsigned, f);
    unsigned r = u + 0x7FFFu + ((u >> 16) & 1u);   // RNE
    return (unsigned short)(r >> 16);
}

// async global->LDS DMA, 16B per lane. dst is wave-uniform base; HW writes lane i at dst + i*16.
static __device__ __forceinline__ void gload_lds16(const unsigned short* g, unsigned char* l) {
    __builtin_amdgcn_global_load_lds((const __attribute__((address_space(1))) unsigned int*)g,
                                     (__attribute__((address_space(3))) unsigned int*)l,
                                     16, 0, 0);
}

// ---------------- K1: s[b,i] = MOD_SCALE * style[b,:]·(mod_weight + fcB@fcA^T)[i,:] + biases
__global__ void k_style(const float* __restrict__ style, const float* __restrict__ mod_weight,
                        const float* __restrict__ mod_bias, const float* __restrict__ fc_lora_A,
                        const float* __restrict__ fc_lora_B, const float* __restrict__ fc_lora_bias,
                        float* __restrict__ s_out) {
    int b = blockIdx.y;
    int i = blockIdx.x * 16 + (threadIdx.x >> 4);
    int jg = threadIdx.x & 15;
    float4 fb = *(const float4*)&fc_lora_B[i * 4];
    const float* st = style + b * STYLE;
    const float* mw = mod_weight + (size_t)i * STYLE;
    float acc = 0.f;
    for (int j = jg * 32; j < jg * 32 + 32; ++j) {
        float4 fa = *(const float4*)&fc_lora_A[j * 4];
        float w = mw[j] + fb.x * fa.x + fb.y * fa.y + fb.z * fa.z + fb.w * fa.w;
        acc += st[j] * w;
    }
    #pragma unroll
    for (int off = 8; off; off >>= 1) acc += __shfl_down(acc, off, 16);
    if (jg == 0) {
        float mod_scale = 1.0f / sqrtf((float)STYLE);
        s_out[b * IC + i] = mod_scale * acc + mod_bias[i] + fc_lora_bias[i];
    }
}

// ---------------- K2: w5 = weight + relu(A·relu(B·inst)); wb swizzled for MFMA A-frags; W2[o][i]
// wb layout: [t(9)][ot(8)][mt(4)][ci(16)][lane(64)][8]
__global__ void k_weight(const float* __restrict__ weight, const float* __restrict__ llB,
                         const float* __restrict__ llBinst, const float* __restrict__ llA,
                         unsigned short* __restrict__ wb, float* __restrict__ W2) {
    int gid = blockIdx.x * 256 + threadIdx.x;      // 262144
    int o = gid >> 9, i = gid & 511;
    float4 vB = *(const float4*)&llB[o * 4];
    float4 vA = *(const float4*)&llA[i * 4];
    const float* wrow = weight + (size_t)(o * IC + i) * 9;
    int lane = ((i >> 3) & 3) * 16 + (o & 15);
    size_t wbase = (((size_t)((o >> 6) * 4 + ((o >> 4) & 3)) * 16 + (i >> 5)) * 64 + lane) * 8 + (i & 7);
    float w2 = 0.f;
    #pragma unroll
    for (int k = 0; k < 9; ++k) {
        float wadd = 0.f;
        #pragma unroll
        for (int bb = 0; bb < 4; ++bb) {
            float bm = vB.x * llBinst[(bb * 4 + 0) * 9 + k] + vB.y * llBinst[(bb * 4 + 1) * 9 + k]
                     + vB.z * llBinst[(bb * 4 + 2) * 9 + k] + vB.w * llBinst[(bb * 4 + 3) * 9 + k];
            bm = fmaxf(bm, 0.f);
            float a = (bb == 0) ? vA.x : (bb == 1) ? vA.y : (bb == 2) ? vA.z : vA.w;
            wadd += a * bm;
        }
        wadd = fmaxf(wadd, 0.f);
        float w5 = wrow[k] + wadd;                 // LORA_ALPHA_CONV = 1
        wb[(size_t)k * 262144 + wbase] = f2bf(w5);
        w2 += w5 * w5;
    }
    W2[gid] = w2;
}

// ---------------- K3: scale[b][o] = CONV_SCALE * rsqrt(CONV_SCALE^2 * sum_i W2[o,i]*s[b,i]^2 + eps)
__global__ void k_scale(const float* __restrict__ W2, const float* __restrict__ s,
                        float* __restrict__ scale) {
    int b = blockIdx.y;
    int o = blockIdx.x * 16 + (threadIdx.x >> 4);
    int jg = threadIdx.x & 15;
    const float* w2r = W2 + (size_t)o * IC;
    const float* sr = s + b * IC;
    float acc = 0.f;
    for (int i = jg * 32; i < jg * 32 + 32; ++i) { float sv = sr[i]; acc += w2r[i] * sv * sv; }
    #pragma unroll
    for (int off = 8; off; off >>= 1) acc += __shfl_down(acc, off, 16);
    if (jg == 0) {
        float cs = 1.0f / sqrtf((float)(IC * 9));
        scale[b * OC + o] = cs * rsqrtf(cs * cs * acc + 1e-8f);
    }
}

// ---------------- K4: NCHW fp32 -> xm[b][hp][ci(16)][u(4)][w(64)][8ch] bf16, modulated by s
__global__ void k_stage_x(const float* __restrict__ x, const float* __restrict__ s,
                          unsigned short* __restrict__ xm) {
    __shared__ float tile[128 * 65];
    int cc = blockIdx.x;   // 0..3 (128-channel chunk)
    int hp = blockIdx.y;   // 0..65
    int b  = blockIdx.z;
    int c0 = cc * 128;
    int tid = threadIdx.x;
    if (hp == 0 || hp == HP - 1) {
        unsigned short* dst = xm + (size_t)(b * HP + hp) * 32768 + cc * 8192;
        uint4 z = make_uint4(0, 0, 0, 0);
        #pragma unroll
        for (int p = 0; p < 4; ++p)
            *(uint4*)(dst + (size_t)(p * 256 + tid) * 8) = z;
        return;
    }
    int h = hp - 1;
    const float* xin = x + (((size_t)b * IC + c0) * H_ + h) * W_;
    #pragma unroll
    for (int p = 0; p < 32; ++p) {
        int idx = p * 256 + tid;
        int c = idx >> 6, w = idx & 63;
        tile[c * 65 + w] = xin[(size_t)c * HW + w];
    }
    __syncthreads();
    const float* sb = s + b * IC + c0;
    #pragma unroll
    for (int p = 0; p < 4; ++p) {
        int idx = p * 256 + tid;               // 0..1023
        int cil = idx >> 8;                    // local ci 0..3
        int u   = (idx >> 6) & 3;
        int w   = idx & 63;
        int cb  = cil * 32 + u * 8;
        unsigned int packed[4];
        #pragma unroll
        for (int k = 0; k < 4; ++k) {
            unsigned lo = f2bf(tile[(cb + 2 * k) * 65 + w] * sb[cb + 2 * k]);
            unsigned hi = f2bf(tile[(cb + 2 * k + 1) * 65 + w] * sb[cb + 2 * k + 1]);
            packed[k] = lo | (hi << 16);
        }
        size_t g = (((size_t)(b * HP + hp) * 16 + (cc * 4 + cil)) * 4 + u) * 64 + w;
        *(uint4*)(xm + g * 8) = make_uint4(packed[0], packed[1], packed[2], packed[3]);
    }
}

// ---------------- K5: conv. 512-thread block = 128 oc x (4 rows x 64 cols); 8 waves =
// 2 oc-halves (ow) x 4 rows (wr), SHARING one x LDS tile. LDS/block unchanged (50688 B)
// -> still 3 blocks/CU but 24 waves/CU = 6 waves/SIMD (was 3): doubles the TLP that hides
// ds_read + af L2 latency, which R7 showed is the binding constraint (pipes ~serial at
// 3 waves/SIMD). Per-wave work/code identical to R3 (VGPR ~72, no spill risk).
// xm DMA demand halves (512 blocks x 384 KB). Weight traffic unchanged.
// XCD pinning: ot2 = wgid%4, so each XCD (wgid%8) hosts a single ot-pair (1.18 MB in L2).
#define STAGE(CN, BSEL)                                                                          \
    _Pragma("unroll")                                                                            \
    for (int j = 0; j < 3; ++j) {                                                                \
        const int g_ = wave * 3 + j;                                                             \
        const int row_ = g_ >> 2, u_ = g_ & 3;                                                   \
        gload_lds16(xmb + ((((size_t)(h0 + row_) * 16 + (CN)) * 4 + u_) * 64 + lane) * 8,        \
                    xs + (size_t)(BSEL) * BUFSZ + (size_t)row_ * ROWSTRIDE + u_ * USTRIDE + 16); \
    }

__global__ __launch_bounds__(512, 4) void k_conv(const unsigned short* __restrict__ wb,
                                                 const unsigned short* __restrict__ xm,
                                                 const float* __restrict__ scale,
                                                 float* __restrict__ out) {
    __shared__ unsigned char xs[2 * BUFSZ];        // 50688 B; epilogue reuses (34816 B)
    const int tid = threadIdx.x;                   // 0..511
    const int wave = tid >> 6, lane = tid & 63;    // 8 waves
    const int l16 = lane & 15, lq = lane >> 4;
    const int ow = wave >> 2;           // 0..1 oc-half
    const int wr = wave & 3;            // 0..3 output row within tile
    const int wgid = blockIdx.x;        // 0..511
    const int ot2 = wgid & 3;           // ot-pair, pinned per XCD (wgid%8 -> XCD; ot2 = xcd&3)
    const int rr = wgid >> 2;           // 0..127
    const int ht = rr & 15;             // 0..15
    const int b  = rr >> 4;             // 0..7
    const int ot = ot2 * 2 + ow;        // 0..7
    const int om = ot * 64;
    const int h0 = ht * 4;

    // zero border col-granules (cols 0 and 65, all 6 rows, all u, BOTH buffers): 96 x 16B
    if (tid < 96) {
        int bsel = tid >= 48;
        int t48 = tid - bsel * 48;
        int row = t48 >> 3;
        int rem = t48 & 7;
        int u = rem >> 1;
        int side = rem & 1;
        uint4 z = make_uint4(0, 0, 0, 0);
        *(uint4*)(xs + bsel * BUFSZ + row * ROWSTRIDE + u * USTRIDE + side * 65 * 16) = z;
    }

    floatx4 acc[4][4];
    #pragma unroll
    for (int mt = 0; mt < 4; ++mt)
        #pragma unroll
        for (int nt = 0; nt < 4; ++nt)
            acc[mt][nt] = (floatx4){0.f, 0.f, 0.f, 0.f};

    // x staging: 24 granule-planes (6 rows x 4 u) split 3 per wave; DMA writes lanes at dst+lane*16
    // (cols 1..64; border cols 0/65 hold the pre-written zeros).
    const unsigned short* xmb = xm + (size_t)b * HP * 32768;
    // weights: swizzled so per-wave load is base + lane*16B (coalesced)
    const unsigned short* wlb = wb + (size_t)ot * 32768 + (size_t)lane * 8;

    // prologue: DMA chunk 0 into buffer 0
    STAGE(0, 0)

    int cur = 0;
    for (int ci = 0; ci < NCHUNK; ++ci) {
        __syncthreads();                // drains DMA for buf[cur] (implicit vmcnt(0)) + makes it visible
        if (ci + 1 < NCHUNK) STAGE(ci + 1, cur ^ 1)   // in flight across compute(ci)
        const unsigned char* buf = xs + (size_t)cur * BUFSZ;
        const unsigned short* wlc = wlb + (size_t)ci * 512;
        #pragma unroll
        for (int kh = 0; kh < 3; ++kh) {
            #pragma unroll
            for (int dw = 0; dw < 3; ++dw) {
                const int t = kh * 3 + dw;
                bf16x8 af[4], bv[4];
                #pragma unroll
                for (int mt = 0; mt < 4; ++mt)
                    af[mt] = *(const bf16x8*)(wlc + (size_t)t * 262144 + mt * 8192);
                #pragma unroll
                for (int nt = 0; nt < 4; ++nt)
                    bv[nt] = *(const bf16x8*)(buf + (size_t)(wr + kh) * ROWSTRIDE + lq * USTRIDE
                                              + (nt * 16 + l16 + dw) * 16);
                #pragma unroll
                for (int mt = 0; mt < 4; ++mt)
                    #pragma unroll
                    for (int nt = 0; nt < 4; ++nt)
                        acc[mt][nt] = __builtin_amdgcn_mfma_f32_16x16x32_bf16(af[mt], bv[nt], acc[mt][nt], 0, 0, 0);
            }
        }
        cur ^= 1;
    }

    // ---- epilogue: scale, then stage through LDS for fully-coalesced float4 stores
    __syncthreads();                    // all waves done with both x buffers
    float* ebuf = (float*)xs + wave * 1088;        // 16 oc-rows x 68 floats per wave (34816 B total)
    const int h = h0 + wr;
    const float* scb = scale + b * OC + om;
    #pragma unroll
    for (int mt = 0; mt < 4; ++mt) {
        float4 sc = *(const float4*)&scb[mt * 16 + lq * 4];
        const float* scp = (const float*)&sc;
        #pragma unroll
        for (int nt = 0; nt < 4; ++nt)
            #pragma unroll
            for (int r2 = 0; r2 < 4; ++r2)
                ebuf[(lq * 4 + r2) * 68 + nt * 16 + l16] = acc[mt][nt][r2] * scp[r2];
        __syncthreads();                // uniform; guarantees write->read ordering
        #pragma unroll
        for (int q = 0; q < 4; ++q) {
            int r0 = q * 4 + (lane >> 4);
            int c0 = (lane & 15) * 4;
            float4 v = *(float4*)&ebuf[r0 * 68 + c0];
            *(float4*)&out[((size_t)(b * OC + om + mt * 16 + r0)) * HW + h * W_ + c0] = v;
        }
        __syncthreads();                // reads done before next mt's writes
    }
}

extern "C" void kernel_launch(void* const* d_in, const int* in_sizes, int n_in,
                              void* d_out, int out_size, void* d_ws, size_t ws_size,
                              hipStream_t stream) {
    const float* input   = (const float*)d_in[0];
    const float* style   = (const float*)d_in[1];
    const float* weight  = (const float*)d_in[2];
    const float* llB     = (const float*)d_in[3];
    const float* llBinst = (const float*)d_in[4];
    const float* llA     = (const float*)d_in[5];
    const float* mod_w   = (const float*)d_in[6];
    const float* mod_b   = (const float*)d_in[7];
    const float* fcA     = (const float*)d_in[8];
    const float* fcB     = (const float*)d_in[9];
    const float* fcBias  = (const float*)d_in[10];
    float* out = (float*)d_out;

    char* ws = (char*)d_ws;
    float* s_ws            = (float*)(ws + 0);                  // 16 KB
    float* scale_ws        = (float*)(ws + 16384);              // 16 KB
    float* W2_ws           = (float*)(ws + 32768);              // 1 MB
    unsigned short* wb_ws  = (unsigned short*)(ws + 32768 + 1048576);          // 4.72 MB
    unsigned short* xm_ws  = (unsigned short*)(ws + 32768 + 1048576 + 4718592); // 34.6 MB

    k_style<<<dim3(32, 8), 256, 0, stream>>>(style, mod_w, mod_b, fcA, fcB, fcBias, s_ws);
    k_weight<<<1024, 256, 0, stream>>>(weight, llB, llBinst, llA, wb_ws, W2_ws);
    k_scale<<<dim3(32, 8), 256, 0, stream>>>(W2_ws, s_ws, scale_ws);
    k_stage_x<<<dim3(4, 66, 8), 256, 0, stream>>>(input, s_ws, xm_ws);
    k_conv<<<512, 512, 0, stream>>>(wb_ws, xm_ws, scale_ws, out);
}

// Round 10
// 277.031 us; speedup vs baseline: 5.0505x; 1.1619x over previous
//
#include <hip/hip_runtime.h>
#include <hip/hip_bf16.h>
#include <math.h>

#define IC 512
#define OC 512
#define STYLE 512
#define BB 8
#define H_ 64
#define W_ 64
#define HW 4096
#define HP 66          // padded rows (zero row above and below)
#define KC 32          // channel chunk per MFMA K-step
#define NCHUNK 16
#define USTRIDE 1056   // bytes per u-granule plane in conv LDS: 66 cols * 16B
#define ROWSTRIDE 4224 // 4 * USTRIDE
#define BUFSZ (6 * ROWSTRIDE)   // 25344 B per x buffer

typedef __attribute__((ext_vector_type(8))) __bf16 bf16x8;
typedef __attribute__((ext_vector_type(4))) float floatx4;

static __device__ __forceinline__ unsigned short f2bf(float f) {
    unsigned u = __builtin_bit_cast(unsigned, f);
    unsigned r = u + 0x7FFFu + ((u >> 16) & 1u);   // RNE
    return (unsigned short)(r >> 16);
}

// async global->LDS DMA, 16B per lane. dst is wave-uniform base; HW writes lane i at dst + i*16.
static __device__ __forceinline__ void gload_lds16(const unsigned short* g, unsigned char* l) {
    __builtin_amdgcn_global_load_lds((const __attribute__((address_space(1))) unsigned int*)g,
                                     (__attribute__((address_space(3))) unsigned int*)l,
                                     16, 0, 0);
}

// ---------------- K1: s[b,i] = MOD_SCALE * style[b,:]·(mod_weight + fcB@fcA^T)[i,:] + biases
__global__ void k_style(const float* __restrict__ style, const float* __restrict__ mod_weight,
                        const float* __restrict__ mod_bias, const float* __restrict__ fc_lora_A,
                        const float* __restrict__ fc_lora_B, const float* __restrict__ fc_lora_bias,
                        float* __restrict__ s_out) {
    int b = blockIdx.y;
    int i = blockIdx.x * 16 + (threadIdx.x >> 4);
    int jg = threadIdx.x & 15;
    float4 fb = *(const float4*)&fc_lora_B[i * 4];
    const float* st = style + b * STYLE;
    const float* mw = mod_weight + (size_t)i * STYLE;
    float acc = 0.f;
    for (int j = jg * 32; j < jg * 32 + 32; ++j) {
        float4 fa = *(const float4*)&fc_lora_A[j * 4];
        float w = mw[j] + fb.x * fa.x + fb.y * fa.y + fb.z * fa.z + fb.w * fa.w;
        acc += st[j] * w;
    }
    #pragma unroll
    for (int off = 8; off; off >>= 1) acc += __shfl_down(acc, off, 16);
    if (jg == 0) {
        float mod_scale = 1.0f / sqrtf((float)STYLE);
        s_out[b * IC + i] = mod_scale * acc + mod_bias[i] + fc_lora_bias[i];
    }
}

// ---------------- K2: w5 = weight + relu(A·relu(B·inst)); wb swizzled for MFMA A-frags; W2[o][i]
// wb layout: [t(9)][ot(8)][mt(4)][ci(16)][lane(64)][8]
__global__ void k_weight(const float* __restrict__ weight, const float* __restrict__ llB,
                         const float* __restrict__ llBinst, const float* __restrict__ llA,
                         unsigned short* __restrict__ wb, float* __restrict__ W2) {
    int gid = blockIdx.x * 256 + threadIdx.x;      // 262144
    int o = gid >> 9, i = gid & 511;
    float4 vB = *(const float4*)&llB[o * 4];
    float4 vA = *(const float4*)&llA[i * 4];
    const float* wrow = weight + (size_t)(o * IC + i) * 9;
    int lane = ((i >> 3) & 3) * 16 + (o & 15);
    size_t wbase = (((size_t)((o >> 6) * 4 + ((o >> 4) & 3)) * 16 + (i >> 5)) * 64 + lane) * 8 + (i & 7);
    float w2 = 0.f;
    #pragma unroll
    for (int k = 0; k < 9; ++k) {
        float wadd = 0.f;
        #pragma unroll
        for (int bb = 0; bb < 4; ++bb) {
            float bm = vB.x * llBinst[(bb * 4 + 0) * 9 + k] + vB.y * llBinst[(bb * 4 + 1) * 9 + k]
                     + vB.z * llBinst[(bb * 4 + 2) * 9 + k] + vB.w * llBinst[(bb * 4 + 3) * 9 + k];
            bm = fmaxf(bm, 0.f);
            float a = (bb == 0) ? vA.x : (bb == 1) ? vA.y : (bb == 2) ? vA.z : vA.w;
            wadd += a * bm;
        }
        wadd = fmaxf(wadd, 0.f);
        float w5 = wrow[k] + wadd;                 // LORA_ALPHA_CONV = 1
        wb[(size_t)k * 262144 + wbase] = f2bf(w5);
        w2 += w5 * w5;
    }
    W2[gid] = w2;
}

// ---------------- K3: scale[b][o] = CONV_SCALE * rsqrt(CONV_SCALE^2 * sum_i W2[o,i]*s[b,i]^2 + eps)
__global__ void k_scale(const float* __restrict__ W2, const float* __restrict__ s,
                        float* __restrict__ scale) {
    int b = blockIdx.y;
    int o = blockIdx.x * 16 + (threadIdx.x >> 4);
    int jg = threadIdx.x & 15;
    const float* w2r = W2 + (size_t)o * IC;
    const float* sr = s + b * IC;
    float acc = 0.f;
    for (int i = jg * 32; i < jg * 32 + 32; ++i) { float sv = sr[i]; acc += w2r[i] * sv * sv; }
    #pragma unroll
    for (int off = 8; off; off >>= 1) acc += __shfl_down(acc, off, 16);
    if (jg == 0) {
        float cs = 1.0f / sqrtf((float)(IC * 9));
        scale[b * OC + o] = cs * rsqrtf(cs * cs * acc + 1e-8f);
    }
}

// ---------------- K4: NCHW fp32 -> xm[b][hp][ci(16)][u(4)][w(64)][8ch] bf16, modulated by s
__global__ void k_stage_x(const float* __restrict__ x, const float* __restrict__ s,
                          unsigned short* __restrict__ xm) {
    __shared__ float tile[128 * 65];
    int cc = blockIdx.x;   // 0..3 (128-channel chunk)
    int hp = blockIdx.y;   // 0..65
    int b  = blockIdx.z;
    int c0 = cc * 128;
    int tid = threadIdx.x;
    if (hp == 0 || hp == HP - 1) {
        unsigned short* dst = xm + (size_t)(b * HP + hp) * 32768 + cc * 8192;
        uint4 z = make_uint4(0, 0, 0, 0);
        #pragma unroll
        for (int p = 0; p < 4; ++p)
            *(uint4*)(dst + (size_t)(p * 256 + tid) * 8) = z;
        return;
    }
    int h = hp - 1;
    const float* xin = x + (((size_t)b * IC + c0) * H_ + h) * W_;
    #pragma unroll
    for (int p = 0; p < 32; ++p) {
        int idx = p * 256 + tid;
        int c = idx >> 6, w = idx & 63;
        tile[c * 65 + w] = xin[(size_t)c * HW + w];
    }
    __syncthreads();
    const float* sb = s + b * IC + c0;
    #pragma unroll
    for (int p = 0; p < 4; ++p) {
        int idx = p * 256 + tid;               // 0..1023
        int cil = idx >> 8;                    // local ci 0..3
        int u   = (idx >> 6) & 3;
        int w   = idx & 63;
        int cb  = cil * 32 + u * 8;
        unsigned int packed[4];
        #pragma unroll
        for (int k = 0; k < 4; ++k) {
            unsigned lo = f2bf(tile[(cb + 2 * k) * 65 + w] * sb[cb + 2 * k]);
            unsigned hi = f2bf(tile[(cb + 2 * k + 1) * 65 + w] * sb[cb + 2 * k + 1]);
            packed[k] = lo | (hi << 16);
        }
        size_t g = (((size_t)(b * HP + hp) * 16 + (cc * 4 + cil)) * 4 + u) * 64 + w;
        *(uint4*)(xm + g * 8) = make_uint4(packed[0], packed[1], packed[2], packed[3]);
    }
}

// ---------------- K5: conv. R9 geometry (512 thr = 2 oc-halves x 4 rows sharing one x tile,
// 512 blocks, ot-pair XCD-pinned) + m201-style per-tap phase alignment:
// each tap = {4 bv ds_reads + 4 af loads (+1 stage-DMA at taps 0..2) -> setprio(1) 16xMFMA
// setprio(0) -> raw s_barrier}. The per-tap barrier keeps the 8 waves in staggered roles
// (one wave's MFMA cluster hides the others' loads); setprio pays ONLY with this split
// (m218b/m224 vs m190-null). Barriers are alignment-only: uniform control flow, no
// intra-chunk cross-wave LDS dependency; chunk-boundary __syncthreads unchanged.
#define STAGE3(CN, BSEL)                                                                         \
    _Pragma("unroll")                                                                            \
    for (int j = 0; j < 3; ++j) {                                                                \
        const int g_ = wave * 3 + j;                                                             \
        const int row_ = g_ >> 2, u_ = g_ & 3;                                                   \
        gload_lds16(xmb + ((((size_t)(h0 + row_) * 16 + (CN)) * 4 + u_) * 64 + lane) * 8,        \
                    xs + (size_t)(BSEL) * BUFSZ + (size_t)row_ * ROWSTRIDE + u_ * USTRIDE + 16); \
    }

#define STAGE1(CN, BSEL, J)                                                                      \
    {   const int g_ = wave * 3 + (J);                                                           \
        const int row_ = g_ >> 2, u_ = g_ & 3;                                                   \
        gload_lds16(xmb + ((((size_t)(h0 + row_) * 16 + (CN)) * 4 + u_) * 64 + lane) * 8,        \
                    xs + (size_t)(BSEL) * BUFSZ + (size_t)row_ * ROWSTRIDE + u_ * USTRIDE + 16); \
    }

__global__ __launch_bounds__(512, 4) void k_conv(const unsigned short* __restrict__ wb,
                                                 const unsigned short* __restrict__ xm,
                                                 const float* __restrict__ scale,
                                                 float* __restrict__ out) {
    __shared__ unsigned char xs[2 * BUFSZ];        // 50688 B; epilogue reuses (34816 B)
    const int tid = threadIdx.x;                   // 0..511
    const int wave = tid >> 6, lane = tid & 63;    // 8 waves
    const int l16 = lane & 15, lq = lane >> 4;
    const int ow = wave >> 2;           // 0..1 oc-half
    const int wr = wave & 3;            // 0..3 output row within tile
    const int wgid = blockIdx.x;        // 0..511
    const int ot2 = wgid & 3;           // ot-pair, pinned per XCD (wgid%8 -> XCD; ot2 = xcd&3)
    const int rr = wgid >> 2;           // 0..127
    const int ht = rr & 15;             // 0..15
    const int b  = rr >> 4;             // 0..7
    const int ot = ot2 * 2 + ow;        // 0..7
    const int om = ot * 64;
    const int h0 = ht * 4;

    // zero border col-granules (cols 0 and 65, all 6 rows, all u, BOTH buffers): 96 x 16B
    if (tid < 96) {
        int bsel = tid >= 48;
        int t48 = tid - bsel * 48;
        int row = t48 >> 3;
        int rem = t48 & 7;
        int u = rem >> 1;
        int side = rem & 1;
        uint4 z = make_uint4(0, 0, 0, 0);
        *(uint4*)(xs + bsel * BUFSZ + row * ROWSTRIDE + u * USTRIDE + side * 65 * 16) = z;
    }

    floatx4 acc[4][4];
    #pragma unroll
    for (int mt = 0; mt < 4; ++mt)
        #pragma unroll
        for (int nt = 0; nt < 4; ++nt)
            acc[mt][nt] = (floatx4){0.f, 0.f, 0.f, 0.f};

    // x staging: 24 granule-planes (6 rows x 4 u) split 3 per wave; DMA writes lanes at dst+lane*16
    const unsigned short* xmb = xm + (size_t)b * HP * 32768;
    // weights: swizzled so per-wave load is base + lane*16B (coalesced)
    const unsigned short* wlb = wb + (size_t)ot * 32768 + (size_t)lane * 8;

    // prologue: DMA chunk 0 into buffer 0
    STAGE3(0, 0)

    int cur = 0;
    for (int ci = 0; ci < NCHUNK; ++ci) {
        __syncthreads();                // chunk boundary: drains DMA for buf[cur] + visibility
        const unsigned char* buf = xs + (size_t)cur * BUFSZ;
        const unsigned short* wlc = wlb + (size_t)ci * 512;
        #pragma unroll
        for (int kh = 0; kh < 3; ++kh) {
            #pragma unroll
            for (int dw = 0; dw < 3; ++dw) {
                const int t = kh * 3 + dw;
                // spread next-chunk stage DMAs across taps 0..2 (one per tap per wave)
                if (t < 3 && ci + 1 < NCHUNK) STAGE1(ci + 1, cur ^ 1, t)
                bf16x8 af[4], bv[4];
                #pragma unroll
                for (int mt = 0; mt < 4; ++mt)
                    af[mt] = *(const bf16x8*)(wlc + (size_t)t * 262144 + mt * 8192);
                #pragma unroll
                for (int nt = 0; nt < 4; ++nt)
                    bv[nt] = *(const bf16x8*)(buf + (size_t)(wr + kh) * ROWSTRIDE + lq * USTRIDE
                                              + (nt * 16 + l16 + dw) * 16);
                __builtin_amdgcn_s_setprio(1);
                #pragma unroll
                for (int mt = 0; mt < 4; ++mt)
                    #pragma unroll
                    for (int nt = 0; nt < 4; ++nt)
                        acc[mt][nt] = __builtin_amdgcn_mfma_f32_16x16x32_bf16(af[mt], bv[nt], acc[mt][nt], 0, 0, 0);
                __builtin_amdgcn_s_setprio(0);
                __builtin_amdgcn_s_barrier();   // per-tap alignment (uniform; no data dep)
            }
        }
        cur ^= 1;
    }

    // ---- epilogue: scale, then stage through LDS for fully-coalesced float4 stores
    __syncthreads();                    // all waves done with both x buffers
    float* ebuf = (float*)xs + wave * 1088;        // 16 oc-rows x 68 floats per wave (34816 B total)
    const int h = h0 + wr;
    const float* scb = scale + b * OC + om;
    #pragma unroll
    for (int mt = 0; mt < 4; ++mt) {
        float4 sc = *(const float4*)&scb[mt * 16 + lq * 4];
        const float* scp = (const float*)&sc;
        #pragma unroll
        for (int nt = 0; nt < 4; ++nt)
            #pragma unroll
            for (int r2 = 0; r2 < 4; ++r2)
                ebuf[(lq * 4 + r2) * 68 + nt * 16 + l16] = acc[mt][nt][r2] * scp[r2];
        __syncthreads();                // uniform; guarantees write->read ordering
        #pragma unroll
        for (int q = 0; q < 4; ++q) {
            int r0 = q * 4 + (lane >> 4);
            int c0 = (lane & 15) * 4;
            float4 v = *(float4*)&ebuf[r0 * 68 + c0];
            *(float4*)&out[((size_t)(b * OC + om + mt * 16 + r0)) * HW + h * W_ + c0] = v;
        }
        __syncthreads();                // reads done before next mt's writes
    }
}

extern "C" void kernel_launch(void* const* d_in, const int* in_sizes, int n_in,
                              void* d_out, int out_size, void* d_ws, size_t ws_size,
                              hipStream_t stream) {
    const float* input   = (const float*)d_in[0];
    const float* style   = (const float*)d_in[1];
    const float* weight  = (const float*)d_in[2];
    const float* llB     = (const float*)d_in[3];
    const float* llBinst = (const float*)d_in[4];
    const float* llA     = (const float*)d_in[5];
    const float* mod_w   = (const float*)d_in[6];
    const float* mod_b   = (const float*)d_in[7];
    const float* fcA     = (const float*)d_in[8];
    const float* fcB     = (const float*)d_in[9];
    const float* fcBias  = (const float*)d_in[10];
    float* out = (float*)d_out;

    char* ws = (char*)d_ws;
    float* s_ws            = (float*)(ws + 0);                  // 16 KB
    float* scale_ws        = (float*)(ws + 16384);              // 16 KB
    float* W2_ws           = (float*)(ws + 32768);              // 1 MB
    unsigned short* wb_ws  = (unsigned short*)(ws + 32768 + 1048576);          // 4.72 MB
    unsigned short* xm_ws  = (unsigned short*)(ws + 32768 + 1048576 + 4718592); // 34.6 MB

    k_style<<<dim3(32, 8), 256, 0, stream>>>(style, mod_w, mod_b, fcA, fcB, fcBias, s_ws);
    k_weight<<<1024, 256, 0, stream>>>(weight, llB, llBinst, llA, wb_ws, W2_ws);
    k_scale<<<dim3(32, 8), 256, 0, stream>>>(W2_ws, s_ws, scale_ws);
    k_stage_x<<<dim3(4, 66, 8), 256, 0, stream>>>(input, s_ws, xm_ws);
    k_conv<<<512, 512, 0, stream>>>(wb_ws, xm_ws, scale_ws, out);
}

// Round 11
// 272.519 us; speedup vs baseline: 5.1341x; 1.0166x over previous
//
#include <hip/hip_runtime.h>
#include <hip/hip_bf16.h>
#include <math.h>

#define IC 512
#define OC 512
#define STYLE 512
#define BB 8
#define H_ 64
#define W_ 64
#define HW 4096
#define HP 66          // padded rows (zero row above and below)
#define KC 32          // channel chunk per MFMA K-step
#define NCHUNK 16
#define USTRIDE 1056   // bytes per u-granule plane in conv LDS: 66 cols * 16B
#define ROWSTRIDE 4224 // 4 * USTRIDE
#define BUFSZ (6 * ROWSTRIDE)   // 25344 B per x buffer

typedef __attribute__((ext_vector_type(8))) __bf16 bf16x8;
typedef __attribute__((ext_vector_type(4))) float floatx4;

static __device__ __forceinline__ unsigned short f2bf(float f) {
    unsigned u = __builtin_bit_cast(unsigned, f);
    unsigned r = u + 0x7FFFu + ((u >> 16) & 1u);   // RNE
    return (unsigned short)(r >> 16);
}

// async global->LDS DMA, 16B per lane. dst is wave-uniform base; HW writes lane i at dst + i*16.
static __device__ __forceinline__ void gload_lds16(const unsigned short* g, unsigned char* l) {
    __builtin_amdgcn_global_load_lds((const __attribute__((address_space(1))) unsigned int*)g,
                                     (__attribute__((address_space(3))) unsigned int*)l,
                                     16, 0, 0);
}

// ---------------- K1: s[b,i] = MOD_SCALE * style[b,:]·(mod_weight + fcB@fcA^T)[i,:] + biases
// grid (32, 8), block 512: i = bx*16 + (tid>>5); jg = tid&31 handles 16 j's. 2 waves/SIMD
// (was 1) to hide the mod_weight load latency of this 1-block/CU dispatch.
__global__ __launch_bounds__(512) void k_style(const float* __restrict__ style,
                        const float* __restrict__ mod_weight,
                        const float* __restrict__ mod_bias, const float* __restrict__ fc_lora_A,
                        const float* __restrict__ fc_lora_B, const float* __restrict__ fc_lora_bias,
                        float* __restrict__ s_out) {
    int b = blockIdx.y;
    int i = blockIdx.x * 16 + (threadIdx.x >> 5);
    int jg = threadIdx.x & 31;
    float4 fb = *(const float4*)&fc_lora_B[i * 4];
    const float* st = style + b * STYLE;
    const float* mw = mod_weight + (size_t)i * STYLE;
    float acc = 0.f;
    for (int j = jg * 16; j < jg * 16 + 16; ++j) {
        float4 fa = *(const float4*)&fc_lora_A[j * 4];
        float w = mw[j] + fb.x * fa.x + fb.y * fa.y + fb.z * fa.z + fb.w * fa.w;
        acc += st[j] * w;
    }
    #pragma unroll
    for (int off = 16; off; off >>= 1) acc += __shfl_down(acc, off, 32);
    if (jg == 0) {
        float mod_scale = 1.0f / sqrtf((float)STYLE);
        s_out[b * IC + i] = mod_scale * acc + mod_bias[i] + fc_lora_bias[i];
    }
}

// ---------------- K2 (fused with old K3): block = one o (512 threads, thread = i).
// Computes w5, writes swizzled wb, and block-reduces scale[b][o] = cs*rsqrt(cs^2 *
// sum_i W2[o,i]*s[b,i]^2 + eps) directly — removes the W2 round-trip and the k_scale launch.
// wb layout: [t(9)][ot(8)][mt(4)][ci(16)][lane(64)][8]
__global__ __launch_bounds__(512) void k_weight(const float* __restrict__ weight,
                         const float* __restrict__ llB,
                         const float* __restrict__ llBinst, const float* __restrict__ llA,
                         const float* __restrict__ s,
                         unsigned short* __restrict__ wb, float* __restrict__ scale) {
    __shared__ float red[8][8];                    // [wave][b]
    int o = blockIdx.x;                            // 0..511
    int i = threadIdx.x;                           // 0..511
    int wv = i >> 6, lane64 = i & 63;
    float4 vB = *(const float4*)&llB[o * 4];
    float4 vA = *(const float4*)&llA[i * 4];
    const float* wrow = weight + (size_t)(o * IC + i) * 9;
    int lane = ((i >> 3) & 3) * 16 + (o & 15);
    size_t wbase = (((size_t)((o >> 6) * 4 + ((o >> 4) & 3)) * 16 + (i >> 5)) * 64 + lane) * 8 + (i & 7);
    float w2 = 0.f;
    #pragma unroll
    for (int k = 0; k < 9; ++k) {
        float wadd = 0.f;
        #pragma unroll
        for (int bb = 0; bb < 4; ++bb) {
            float bm = vB.x * llBinst[(bb * 4 + 0) * 9 + k] + vB.y * llBinst[(bb * 4 + 1) * 9 + k]
                     + vB.z * llBinst[(bb * 4 + 2) * 9 + k] + vB.w * llBinst[(bb * 4 + 3) * 9 + k];
            bm = fmaxf(bm, 0.f);
            float a = (bb == 0) ? vA.x : (bb == 1) ? vA.y : (bb == 2) ? vA.z : vA.w;
            wadd += a * bm;
        }
        wadd = fmaxf(wadd, 0.f);
        float w5 = wrow[k] + wadd;                 // LORA_ALPHA_CONV = 1
        wb[(size_t)k * 262144 + wbase] = f2bf(w5);
        w2 += w5 * w5;
    }
    // per-b partials: w2 * s[b,i]^2, wave-reduced then cross-wave via tiny LDS
    float partial[8];
    #pragma unroll
    for (int b = 0; b < 8; ++b) {
        float sv = s[b * IC + i];
        partial[b] = w2 * sv * sv;
    }
    #pragma unroll
    for (int off = 32; off; off >>= 1)
        #pragma unroll
        for (int b = 0; b < 8; ++b)
            partial[b] += __shfl_down(partial[b], off, 64);
    if (lane64 == 0)
        #pragma unroll
        for (int b = 0; b < 8; ++b)
            red[wv][b] = partial[b];
    __syncthreads();
    if (i < 8) {
        float acc = 0.f;
        #pragma unroll
        for (int w = 0; w < 8; ++w) acc += red[w][i];
        float cs = 1.0f / sqrtf((float)(IC * 9));
        scale[i * OC + o] = cs * rsqrtf(cs * cs * acc + 1e-8f);
    }
}

// ---------------- K4: NCHW fp32 -> xm[b][hp][ci(16)][u(4)][w(64)][8ch] bf16, modulated by s
__global__ void k_stage_x(const float* __restrict__ x, const float* __restrict__ s,
                          unsigned short* __restrict__ xm) {
    __shared__ float tile[128 * 65];
    int cc = blockIdx.x;   // 0..3 (128-channel chunk)
    int hp = blockIdx.y;   // 0..65
    int b  = blockIdx.z;
    int c0 = cc * 128;
    int tid = threadIdx.x;
    if (hp == 0 || hp == HP - 1) {
        unsigned short* dst = xm + (size_t)(b * HP + hp) * 32768 + cc * 8192;
        uint4 z = make_uint4(0, 0, 0, 0);
        #pragma unroll
        for (int p = 0; p < 4; ++p)
            *(uint4*)(dst + (size_t)(p * 256 + tid) * 8) = z;
        return;
    }
    int h = hp - 1;
    const float* xin = x + (((size_t)b * IC + c0) * H_ + h) * W_;
    #pragma unroll
    for (int p = 0; p < 32; ++p) {
        int idx = p * 256 + tid;
        int c = idx >> 6, w = idx & 63;
        tile[c * 65 + w] = xin[(size_t)c * HW + w];
    }
    __syncthreads();
    const float* sb = s + b * IC + c0;
    #pragma unroll
    for (int p = 0; p < 4; ++p) {
        int idx = p * 256 + tid;               // 0..1023
        int cil = idx >> 8;                    // local ci 0..3
        int u   = (idx >> 6) & 3;
        int w   = idx & 63;
        int cb  = cil * 32 + u * 8;
        unsigned int packed[4];
        #pragma unroll
        for (int k = 0; k < 4; ++k) {
            unsigned lo = f2bf(tile[(cb + 2 * k) * 65 + w] * sb[cb + 2 * k]);
            unsigned hi = f2bf(tile[(cb + 2 * k + 1) * 65 + w] * sb[cb + 2 * k + 1]);
            packed[k] = lo | (hi << 16);
        }
        size_t g = (((size_t)(b * HP + hp) * 16 + (cc * 4 + cil)) * 4 + u) * 64 + w;
        *(uint4*)(xm + g * 8) = make_uint4(packed[0], packed[1], packed[2], packed[3]);
    }
}

// ---------------- K5: conv. R9 geometry (512 thr = 2 oc-halves x 4 rows sharing one x tile,
// 512 blocks, ot-pair XCD-pinned) + m201-style per-tap phase alignment:
// each tap = {4 bv ds_reads + 4 af loads (+1 stage-DMA at taps 0..2) -> setprio(1) 16xMFMA
// setprio(0) -> raw s_barrier}. MEASURED WINNER (R10: 132 us, MfmaUtil 53%) — unchanged.
#define STAGE3(CN, BSEL)                                                                         \
    _Pragma("unroll")                                                                            \
    for (int j = 0; j < 3; ++j) {                                                                \
        const int g_ = wave * 3 + j;                                                             \
        const int row_ = g_ >> 2, u_ = g_ & 3;                                                   \
        gload_lds16(xmb + ((((size_t)(h0 + row_) * 16 + (CN)) * 4 + u_) * 64 + lane) * 8,        \
                    xs + (size_t)(BSEL) * BUFSZ + (size_t)row_ * ROWSTRIDE + u_ * USTRIDE + 16); \
    }

#define STAGE1(CN, BSEL, J)                                                                      \
    {   const int g_ = wave * 3 + (J);                                                           \
        const int row_ = g_ >> 2, u_ = g_ & 3;                                                   \
        gload_lds16(xmb + ((((size_t)(h0 + row_) * 16 + (CN)) * 4 + u_) * 64 + lane) * 8,        \
                    xs + (size_t)(BSEL) * BUFSZ + (size_t)row_ * ROWSTRIDE + u_ * USTRIDE + 16); \
    }

__global__ __launch_bounds__(512, 4) void k_conv(const unsigned short* __restrict__ wb,
                                                 const unsigned short* __restrict__ xm,
                                                 const float* __restrict__ scale,
                                                 float* __restrict__ out) {
    __shared__ unsigned char xs[2 * BUFSZ];        // 50688 B; epilogue reuses (34816 B)
    const int tid = threadIdx.x;                   // 0..511
    const int wave = tid >> 6, lane = tid & 63;    // 8 waves
    const int l16 = lane & 15, lq = lane >> 4;
    const int ow = wave >> 2;           // 0..1 oc-half
    const int wr = wave & 3;            // 0..3 output row within tile
    const int wgid = blockIdx.x;        // 0..511
    const int ot2 = wgid & 3;           // ot-pair, pinned per XCD (wgid%8 -> XCD; ot2 = xcd&3)
    const int rr = wgid >> 2;           // 0..127
    const int ht = rr & 15;             // 0..15
    const int b  = rr >> 4;             // 0..7
    const int ot = ot2 * 2 + ow;        // 0..7
    const int om = ot * 64;
    const int h0 = ht * 4;

    // zero border col-granules (cols 0 and 65, all 6 rows, all u, BOTH buffers): 96 x 16B
    if (tid < 96) {
        int bsel = tid >= 48;
        int t48 = tid - bsel * 48;
        int row = t48 >> 3;
        int rem = t48 & 7;
        int u = rem >> 1;
        int side = rem & 1;
        uint4 z = make_uint4(0, 0, 0, 0);
        *(uint4*)(xs + bsel * BUFSZ + row * ROWSTRIDE + u * USTRIDE + side * 65 * 16) = z;
    }

    floatx4 acc[4][4];
    #pragma unroll
    for (int mt = 0; mt < 4; ++mt)
        #pragma unroll
        for (int nt = 0; nt < 4; ++nt)
            acc[mt][nt] = (floatx4){0.f, 0.f, 0.f, 0.f};

    // x staging: 24 granule-planes (6 rows x 4 u) split 3 per wave; DMA writes lanes at dst+lane*16
    const unsigned short* xmb = xm + (size_t)b * HP * 32768;
    // weights: swizzled so per-wave load is base + lane*16B (coalesced)
    const unsigned short* wlb = wb + (size_t)ot * 32768 + (size_t)lane * 8;

    // prologue: DMA chunk 0 into buffer 0
    STAGE3(0, 0)

    int cur = 0;
    for (int ci = 0; ci < NCHUNK; ++ci) {
        __syncthreads();                // chunk boundary: drains DMA for buf[cur] + visibility
        const unsigned char* buf = xs + (size_t)cur * BUFSZ;
        const unsigned short* wlc = wlb + (size_t)ci * 512;
        #pragma unroll
        for (int kh = 0; kh < 3; ++kh) {
            #pragma unroll
            for (int dw = 0; dw < 3; ++dw) {
                const int t = kh * 3 + dw;
                // spread next-chunk stage DMAs across taps 0..2 (one per tap per wave)
                if (t < 3 && ci + 1 < NCHUNK) STAGE1(ci + 1, cur ^ 1, t)
                bf16x8 af[4], bv[4];
                #pragma unroll
                for (int mt = 0; mt < 4; ++mt)
                    af[mt] = *(const bf16x8*)(wlc + (size_t)t * 262144 + mt * 8192);
                #pragma unroll
                for (int nt = 0; nt < 4; ++nt)
                    bv[nt] = *(const bf16x8*)(buf + (size_t)(wr + kh) * ROWSTRIDE + lq * USTRIDE
                                              + (nt * 16 + l16 + dw) * 16);
                __builtin_amdgcn_s_setprio(1);
                #pragma unroll
                for (int mt = 0; mt < 4; ++mt)
                    #pragma unroll
                    for (int nt = 0; nt < 4; ++nt)
                        acc[mt][nt] = __builtin_amdgcn_mfma_f32_16x16x32_bf16(af[mt], bv[nt], acc[mt][nt], 0, 0, 0);
                __builtin_amdgcn_s_setprio(0);
                __builtin_amdgcn_s_barrier();   // per-tap alignment (uniform; no data dep)
            }
        }
        cur ^= 1;
    }

    // ---- epilogue: scale, then stage through LDS for fully-coalesced float4 stores
    __syncthreads();                    // all waves done with both x buffers
    float* ebuf = (float*)xs + wave * 1088;        // 16 oc-rows x 68 floats per wave (34816 B total)
    const int h = h0 + wr;
    const float* scb = scale + b * OC + om;
    #pragma unroll
    for (int mt = 0; mt < 4; ++mt) {
        float4 sc = *(const float4*)&scb[mt * 16 + lq * 4];
        const float* scp = (const float*)&sc;
        #pragma unroll
        for (int nt = 0; nt < 4; ++nt)
            #pragma unroll
            for (int r2 = 0; r2 < 4; ++r2)
                ebuf[(lq * 4 + r2) * 68 + nt * 16 + l16] = acc[mt][nt][r2] * scp[r2];
        __syncthreads();                // uniform; guarantees write->read ordering
        #pragma unroll
        for (int q = 0; q < 4; ++q) {
            int r0 = q * 4 + (lane >> 4);
            int c0 = (lane & 15) * 4;
            float4 v = *(float4*)&ebuf[r0 * 68 + c0];
            *(float4*)&out[((size_t)(b * OC + om + mt * 16 + r0)) * HW + h * W_ + c0] = v;
        }
        __syncthreads();                // reads done before next mt's writes
    }
}

extern "C" void kernel_launch(void* const* d_in, const int* in_sizes, int n_in,
                              void* d_out, int out_size, void* d_ws, size_t ws_size,
                              hipStream_t stream) {
    const float* input   = (const float*)d_in[0];
    const float* style   = (const float*)d_in[1];
    const float* weight  = (const float*)d_in[2];
    const float* llB     = (const float*)d_in[3];
    const float* llBinst = (const float*)d_in[4];
    const float* llA     = (const float*)d_in[5];
    const float* mod_w   = (const float*)d_in[6];
    const float* mod_b   = (const float*)d_in[7];
    const float* fcA     = (const float*)d_in[8];
    const float* fcB     = (const float*)d_in[9];
    const float* fcBias  = (const float*)d_in[10];
    float* out = (float*)d_out;

    char* ws = (char*)d_ws;
    float* s_ws            = (float*)(ws + 0);                  // 16 KB
    float* scale_ws        = (float*)(ws + 16384);              // 16 KB
    unsigned short* wb_ws  = (unsigned short*)(ws + 32768);                    // 4.72 MB
    unsigned short* xm_ws  = (unsigned short*)(ws + 32768 + 4718592);          // 34.6 MB

    k_style<<<dim3(32, 8), 512, 0, stream>>>(style, mod_w, mod_b, fcA, fcB, fcBias, s_ws);
    k_weight<<<512, 512, 0, stream>>>(weight, llB, llBinst, llA, s_ws, wb_ws, scale_ws);
    k_stage_x<<<dim3(4, 66, 8), 256, 0, stream>>>(input, s_ws, xm_ws);
    k_conv<<<512, 512, 0, stream>>>(wb_ws, xm_ws, scale_ws, out);
}

// Round 12
// 270.742 us; speedup vs baseline: 5.1678x; 1.0066x over previous
//
#include <hip/hip_runtime.h>
#include <hip/hip_bf16.h>
#include <math.h>

#define IC 512
#define OC 512
#define STYLE 512
#define BB 8
#define H_ 64
#define W_ 64
#define HW 4096
#define HP 66          // padded rows (zero row above and below)
#define KC 32          // channel chunk per MFMA K-step
#define NCHUNK 16
#define USTRIDE 1056   // bytes per u-granule plane in conv LDS: 66 cols * 16B
#define ROWSTRIDE 4224 // 4 * USTRIDE
#define BUFSZ (6 * ROWSTRIDE)   // 25344 B per x buffer

typedef __attribute__((ext_vector_type(8))) __bf16 bf16x8;
typedef __attribute__((ext_vector_type(4))) float floatx4;

static __device__ __forceinline__ unsigned short f2bf(float f) {
    unsigned u = __builtin_bit_cast(unsigned, f);
    unsigned r = u + 0x7FFFu + ((u >> 16) & 1u);   // RNE
    return (unsigned short)(r >> 16);
}

// async global->LDS DMA, 16B per lane. dst is wave-uniform base; HW writes lane i at dst + i*16.
static __device__ __forceinline__ void gload_lds16(const unsigned short* g, unsigned char* l) {
    __builtin_amdgcn_global_load_lds((const __attribute__((address_space(1))) unsigned int*)g,
                                     (__attribute__((address_space(3))) unsigned int*)l,
                                     16, 0, 0);
}

// ---------------- K1: s[b,i] = MOD_SCALE * style[b,:]·(mod_weight + fcB@fcA^T)[i,:] + biases
// grid (32, 8), block 512: i = bx*16 + (tid>>5); jg = tid&31 handles 16 j's.
__global__ __launch_bounds__(512) void k_style(const float* __restrict__ style,
                        const float* __restrict__ mod_weight,
                        const float* __restrict__ mod_bias, const float* __restrict__ fc_lora_A,
                        const float* __restrict__ fc_lora_B, const float* __restrict__ fc_lora_bias,
                        float* __restrict__ s_out) {
    int b = blockIdx.y;
    int i = blockIdx.x * 16 + (threadIdx.x >> 5);
    int jg = threadIdx.x & 31;
    float4 fb = *(const float4*)&fc_lora_B[i * 4];
    const float* st = style + b * STYLE;
    const float* mw = mod_weight + (size_t)i * STYLE;
    float acc = 0.f;
    for (int j = jg * 16; j < jg * 16 + 16; ++j) {
        float4 fa = *(const float4*)&fc_lora_A[j * 4];
        float w = mw[j] + fb.x * fa.x + fb.y * fa.y + fb.z * fa.z + fb.w * fa.w;
        acc += st[j] * w;
    }
    #pragma unroll
    for (int off = 16; off; off >>= 1) acc += __shfl_down(acc, off, 32);
    if (jg == 0) {
        float mod_scale = 1.0f / sqrtf((float)STYLE);
        s_out[b * IC + i] = mod_scale * acc + mod_bias[i] + fc_lora_bias[i];
    }
}

// ---------------- K2 (merged): block-specialized prep dispatch.
// blocks [0,512):   weight+scale path (block = one o): w5 -> swizzled wb + block-reduced scale[b][o]
// blocks [512,2624): stage_x path: NCHW fp32 -> xm[b][hp][ci][u][w][8ch] bf16, modulated by s
// Both depend only on s; merging lets the compute-bound weight blocks and the BW-bound stage
// blocks co-execute (m114 pipe overlap) instead of serializing across two launches.
// wb layout: [t(9)][ot(8)][mt(4)][ci(16)][lane(64)][8]
__global__ __launch_bounds__(512) void k_prep(const float* __restrict__ weight,
                         const float* __restrict__ llB,
                         const float* __restrict__ llBinst, const float* __restrict__ llA,
                         const float* __restrict__ s,
                         unsigned short* __restrict__ wb, float* __restrict__ scale,
                         const float* __restrict__ x, unsigned short* __restrict__ xm) {
    __shared__ float tile[128 * 65];               // stage path; weight path aliases first 64 floats
    const int bid = blockIdx.x;
    if (bid < 512) {
        // ================= weight + scale path =================
        float (*red)[8] = (float(*)[8])tile;       // [wave][b]
        int o = bid;                               // 0..511
        int i = threadIdx.x;                       // 0..511
        int wv = i >> 6, lane64 = i & 63;
        float4 vB = *(const float4*)&llB[o * 4];
        float4 vA = *(const float4*)&llA[i * 4];
        const float* wrow = weight + (size_t)(o * IC + i) * 9;
        int lane = ((i >> 3) & 3) * 16 + (o & 15);
        size_t wbase = (((size_t)((o >> 6) * 4 + ((o >> 4) & 3)) * 16 + (i >> 5)) * 64 + lane) * 8 + (i & 7);
        float w2 = 0.f;
        #pragma unroll
        for (int k = 0; k < 9; ++k) {
            float wadd = 0.f;
            #pragma unroll
            for (int bb = 0; bb < 4; ++bb) {
                float bm = vB.x * llBinst[(bb * 4 + 0) * 9 + k] + vB.y * llBinst[(bb * 4 + 1) * 9 + k]
                         + vB.z * llBinst[(bb * 4 + 2) * 9 + k] + vB.w * llBinst[(bb * 4 + 3) * 9 + k];
                bm = fmaxf(bm, 0.f);
                float a = (bb == 0) ? vA.x : (bb == 1) ? vA.y : (bb == 2) ? vA.z : vA.w;
                wadd += a * bm;
            }
            wadd = fmaxf(wadd, 0.f);
            float w5 = wrow[k] + wadd;             // LORA_ALPHA_CONV = 1
            wb[(size_t)k * 262144 + wbase] = f2bf(w5);
            w2 += w5 * w5;
        }
        // per-b partials: w2 * s[b,i]^2, wave-reduced then cross-wave via tiny LDS
        float partial[8];
        #pragma unroll
        for (int b = 0; b < 8; ++b) {
            float sv = s[b * IC + i];
            partial[b] = w2 * sv * sv;
        }
        #pragma unroll
        for (int off = 32; off; off >>= 1)
            #pragma unroll
            for (int b = 0; b < 8; ++b)
                partial[b] += __shfl_down(partial[b], off, 64);
        if (lane64 == 0)
            #pragma unroll
            for (int b = 0; b < 8; ++b)
                red[wv][b] = partial[b];
        __syncthreads();
        if (i < 8) {
            float acc = 0.f;
            #pragma unroll
            for (int w = 0; w < 8; ++w) acc += red[w][i];
            float cs = 1.0f / sqrtf((float)(IC * 9));
            scale[i * OC + o] = cs * rsqrtf(cs * cs * acc + 1e-8f);
        }
    } else {
        // ================= stage_x path (512 threads) =================
        int sb_ = bid - 512;                       // 0..2111 = cc + 4*(hp + 66*b)
        int cc = sb_ & 3;                          // 0..3 (128-channel chunk)
        int t2 = sb_ >> 2;                         // 0..527
        int hp = t2 % 66;                          // 0..65
        int b  = t2 / 66;                          // 0..7
        int c0 = cc * 128;
        int tid = threadIdx.x;                     // 0..511
        if (hp == 0 || hp == HP - 1) {
            unsigned short* dst = xm + (size_t)(b * HP + hp) * 32768 + cc * 8192;
            uint4 z = make_uint4(0, 0, 0, 0);
            #pragma unroll
            for (int p = 0; p < 2; ++p)
                *(uint4*)(dst + (size_t)(p * 512 + tid) * 8) = z;
            return;
        }
        int h = hp - 1;
        const float* xin = x + (((size_t)b * IC + c0) * H_ + h) * W_;
        #pragma unroll
        for (int p = 0; p < 16; ++p) {
            int idx = p * 512 + tid;
            int c = idx >> 6, w = idx & 63;
            tile[c * 65 + w] = xin[(size_t)c * HW + w];
        }
        __syncthreads();
        const float* sb2 = s + b * IC + c0;
        #pragma unroll
        for (int p = 0; p < 2; ++p) {
            int idx = p * 512 + tid;               // 0..1023
            int cil = idx >> 8;                    // local ci 0..3
            int u   = (idx >> 6) & 3;
            int w   = idx & 63;
            int cb  = cil * 32 + u * 8;
            unsigned int packed[4];
            #pragma unroll
            for (int k = 0; k < 4; ++k) {
                unsigned lo = f2bf(tile[(cb + 2 * k) * 65 + w] * sb2[cb + 2 * k]);
                unsigned hi = f2bf(tile[(cb + 2 * k + 1) * 65 + w] * sb2[cb + 2 * k + 1]);
                packed[k] = lo | (hi << 16);
            }
            size_t g = (((size_t)(b * HP + hp) * 16 + (cc * 4 + cil)) * 4 + u) * 64 + w;
            *(uint4*)(xm + g * 8) = make_uint4(packed[0], packed[1], packed[2], packed[3]);
        }
    }
}

// ---------------- K5: conv. R9 geometry (512 thr = 2 oc-halves x 4 rows sharing one x tile,
// 512 blocks, ot-pair XCD-pinned) + m201-style per-tap phase alignment:
// each tap = {4 bv ds_reads + 4 af loads (+1 stage-DMA at taps 0..2) -> setprio(1) 16xMFMA
// setprio(0) -> raw s_barrier}. MEASURED WINNER (R10: 132 us, MfmaUtil 53%) — unchanged.
#define STAGE3(CN, BSEL)                                                                         \
    _Pragma("unroll")                                                                            \
    for (int j = 0; j < 3; ++j) {                                                                \
        const int g_ = wave * 3 + j;                                                             \
        const int row_ = g_ >> 2, u_ = g_ & 3;                                                   \
        gload_lds16(xmb + ((((size_t)(h0 + row_) * 16 + (CN)) * 4 + u_) * 64 + lane) * 8,        \
                    xs + (size_t)(BSEL) * BUFSZ + (size_t)row_ * ROWSTRIDE + u_ * USTRIDE + 16); \
    }

#define STAGE1(CN, BSEL, J)                                                                      \
    {   const int g_ = wave * 3 + (J);                                                           \
        const int row_ = g_ >> 2, u_ = g_ & 3;                                                   \
        gload_lds16(xmb + ((((size_t)(h0 + row_) * 16 + (CN)) * 4 + u_) * 64 + lane) * 8,        \
                    xs + (size_t)(BSEL) * BUFSZ + (size_t)row_ * ROWSTRIDE + u_ * USTRIDE + 16); \
    }

__global__ __launch_bounds__(512, 4) void k_conv(const unsigned short* __restrict__ wb,
                                                 const unsigned short* __restrict__ xm,
                                                 const float* __restrict__ scale,
                                                 float* __restrict__ out) {
    __shared__ unsigned char xs[2 * BUFSZ];        // 50688 B; epilogue reuses (34816 B)
    const int tid = threadIdx.x;                   // 0..511
    const int wave = tid >> 6, lane = tid & 63;    // 8 waves
    const int l16 = lane & 15, lq = lane >> 4;
    const int ow = wave >> 2;           // 0..1 oc-half
    const int wr = wave & 3;            // 0..3 output row within tile
    const int wgid = blockIdx.x;        // 0..511
    const int ot2 = wgid & 3;           // ot-pair, pinned per XCD (wgid%8 -> XCD; ot2 = xcd&3)
    const int rr = wgid >> 2;           // 0..127
    const int ht = rr & 15;             // 0..15
    const int b  = rr >> 4;             // 0..7
    const int ot = ot2 * 2 + ow;        // 0..7
    const int om = ot * 64;
    const int h0 = ht * 4;

    // zero border col-granules (cols 0 and 65, all 6 rows, all u, BOTH buffers): 96 x 16B
    if (tid < 96) {
        int bsel = tid >= 48;
        int t48 = tid - bsel * 48;
        int row = t48 >> 3;
        int rem = t48 & 7;
        int u = rem >> 1;
        int side = rem & 1;
        uint4 z = make_uint4(0, 0, 0, 0);
        *(uint4*)(xs + bsel * BUFSZ + row * ROWSTRIDE + u * USTRIDE + side * 65 * 16) = z;
    }

    floatx4 acc[4][4];
    #pragma unroll
    for (int mt = 0; mt < 4; ++mt)
        #pragma unroll
        for (int nt = 0; nt < 4; ++nt)
            acc[mt][nt] = (floatx4){0.f, 0.f, 0.f, 0.f};

    // x staging: 24 granule-planes (6 rows x 4 u) split 3 per wave; DMA writes lanes at dst+lane*16
    const unsigned short* xmb = xm + (size_t)b * HP * 32768;
    // weights: swizzled so per-wave load is base + lane*16B (coalesced)
    const unsigned short* wlb = wb + (size_t)ot * 32768 + (size_t)lane * 8;

    // prologue: DMA chunk 0 into buffer 0
    STAGE3(0, 0)

    int cur = 0;
    for (int ci = 0; ci < NCHUNK; ++ci) {
        __syncthreads();                // chunk boundary: drains DMA for buf[cur] + visibility
        const unsigned char* buf = xs + (size_t)cur * BUFSZ;
        const unsigned short* wlc = wlb + (size_t)ci * 512;
        #pragma unroll
        for (int kh = 0; kh < 3; ++kh) {
            #pragma unroll
            for (int dw = 0; dw < 3; ++dw) {
                const int t = kh * 3 + dw;
                // spread next-chunk stage DMAs across taps 0..2 (one per tap per wave)
                if (t < 3 && ci + 1 < NCHUNK) STAGE1(ci + 1, cur ^ 1, t)
                bf16x8 af[4], bv[4];
                #pragma unroll
                for (int mt = 0; mt < 4; ++mt)
                    af[mt] = *(const bf16x8*)(wlc + (size_t)t * 262144 + mt * 8192);
                #pragma unroll
                for (int nt = 0; nt < 4; ++nt)
                    bv[nt] = *(const bf16x8*)(buf + (size_t)(wr + kh) * ROWSTRIDE + lq * USTRIDE
                                              + (nt * 16 + l16 + dw) * 16);
                __builtin_amdgcn_s_setprio(1);
                #pragma unroll
                for (int mt = 0; mt < 4; ++mt)
                    #pragma unroll
                    for (int nt = 0; nt < 4; ++nt)
                        acc[mt][nt] = __builtin_amdgcn_mfma_f32_16x16x32_bf16(af[mt], bv[nt], acc[mt][nt], 0, 0, 0);
                __builtin_amdgcn_s_setprio(0);
                __builtin_amdgcn_s_barrier();   // per-tap alignment (uniform; no data dep)
            }
        }
        cur ^= 1;
    }

    // ---- epilogue: scale, then stage through LDS for fully-coalesced float4 stores
    __syncthreads();                    // all waves done with both x buffers
    float* ebuf = (float*)xs + wave * 1088;        // 16 oc-rows x 68 floats per wave (34816 B total)
    const int h = h0 + wr;
    const float* scb = scale + b * OC + om;
    #pragma unroll
    for (int mt = 0; mt < 4; ++mt) {
        float4 sc = *(const float4*)&scb[mt * 16 + lq * 4];
        const float* scp = (const float*)&sc;
        #pragma unroll
        for (int nt = 0; nt < 4; ++nt)
            #pragma unroll
            for (int r2 = 0; r2 < 4; ++r2)
                ebuf[(lq * 4 + r2) * 68 + nt * 16 + l16] = acc[mt][nt][r2] * scp[r2];
        __syncthreads();                // uniform; guarantees write->read ordering
        #pragma unroll
        for (int q = 0; q < 4; ++q) {
            int r0 = q * 4 + (lane >> 4);
            int c0 = (lane & 15) * 4;
            float4 v = *(float4*)&ebuf[r0 * 68 + c0];
            *(float4*)&out[((size_t)(b * OC + om + mt * 16 + r0)) * HW + h * W_ + c0] = v;
        }
        __syncthreads();                // reads done before next mt's writes
    }
}

extern "C" void kernel_launch(void* const* d_in, const int* in_sizes, int n_in,
                              void* d_out, int out_size, void* d_ws, size_t ws_size,
                              hipStream_t stream) {
    const float* input   = (const float*)d_in[0];
    const float* style   = (const float*)d_in[1];
    const float* weight  = (const float*)d_in[2];
    const float* llB     = (const float*)d_in[3];
    const float* llBinst = (const float*)d_in[4];
    const float* llA     = (const float*)d_in[5];
    const float* mod_w   = (const float*)d_in[6];
    const float* mod_b   = (const float*)d_in[7];
    const float* fcA     = (const float*)d_in[8];
    const float* fcB     = (const float*)d_in[9];
    const float* fcBias  = (const float*)d_in[10];
    float* out = (float*)d_out;

    char* ws = (char*)d_ws;
    float* s_ws            = (float*)(ws + 0);                  // 16 KB
    float* scale_ws        = (float*)(ws + 16384);              // 16 KB
    unsigned short* wb_ws  = (unsigned short*)(ws + 32768);                    // 4.72 MB
    unsigned short* xm_ws  = (unsigned short*)(ws + 32768 + 4718592);          // 34.6 MB

    k_style<<<dim3(32, 8), 512, 0, stream>>>(style, mod_w, mod_b, fcA, fcB, fcBias, s_ws);
    k_prep<<<2624, 512, 0, stream>>>(weight, llB, llBinst, llA, s_ws, wb_ws, scale_ws,
                                     input, xm_ws);
    k_conv<<<512, 512, 0, stream>>>(wb_ws, xm_ws, scale_ws, out);
}